// Round 19
// baseline (1447.882 us; speedup 1.0000x reference)
//
#include <hip/hip_runtime.h>
#include <hip/hip_fp16.h>
#include <math.h>

#define B_    512
#define T_    75
#define IN_   768
#define H_    256
#define NSPAN 8
#define OUTD  2
#define NDAYS 10
#define EPS_  1e-5f
#define MAXN_ 0.999f
#define CLIP_ (1.0f - 1e-7f)

typedef short bf16x8 __attribute__((ext_vector_type(8)));
typedef float f32x4 __attribute__((ext_vector_type(4)));

// ---------------- wave helpers (wave = 64 lanes) ----------------
// DPP-based wave reduction: VALU pipe instead of ds_swizzle.
template<int CTRL, int RMASK>
__device__ __forceinline__ float dppadd_(float v) {
    return v + __int_as_float(__builtin_amdgcn_update_dpp(
        0, __float_as_int(v), CTRL, RMASK, 0xf, true));
}
__device__ __forceinline__ float wred(float v) {
    v = dppadd_<0x111, 0xf>(v);   // row_shr:1
    v = dppadd_<0x112, 0xf>(v);   // row_shr:2
    v = dppadd_<0x114, 0xf>(v);   // row_shr:4
    v = dppadd_<0x118, 0xf>(v);   // row_shr:8
    v = dppadd_<0x142, 0xa>(v);   // row_bcast:15
    v = dppadd_<0x143, 0xc>(v);   // row_bcast:31; lane63 = total
    return __int_as_float(__builtin_amdgcn_readlane(__float_as_int(v), 63));
}
__device__ __forceinline__ float artanh_(float x) {
    x = fminf(x, CLIP_);
    return 0.5f * logf((1.f + x) / (1.f - x));
}
__device__ __forceinline__ float sigm_(float x) { return 1.f / (1.f + expf(-x)); }
__device__ __forceinline__ float h2f_(unsigned short u) {
    union { unsigned short us; __half h; } cv; cv.us = u;
    return __half2float(cv.h);
}
__device__ __forceinline__ unsigned int packf16(float a, float b) {
    union { __half h; unsigned short us; } ca, cb;
    ca.h = __float2half(a); cb.h = __float2half(b);
    return (unsigned int)ca.us | ((unsigned int)cb.us << 16);
}
__device__ __forceinline__ unsigned short f2bf_(float f) {  // RNE f32->bf16
    union { float f; unsigned u; } c; c.f = f;
    unsigned r = c.u + 0x7fff + ((c.u >> 16) & 1);
    return (unsigned short)(r >> 16);
}
// f16-pair dot product with f32 accumulator
__device__ __forceinline__ float dot2_(unsigned int w, unsigned int h, float acc) {
#if __has_builtin(__builtin_amdgcn_fdot2)
    typedef _Float16 h2_t __attribute__((ext_vector_type(2)));
    union { unsigned int u; h2_t v; } a, b;
    a.u = w; b.u = h;
    return __builtin_amdgcn_fdot2(a.v, b.v, acc, false);
#else
    float wx = h2f_((unsigned short)(w & 0xffff)), wy = h2f_((unsigned short)(w >> 16));
    float hx = h2f_((unsigned short)(h & 0xffff)), hy = h2f_((unsigned short)(h >> 16));
    return fmaf(wy, hy, fmaf(wx, hx, acc));
#endif
}
// ---- fast-math (encoder hot path). Args are wave-uniform norms >= 0. ----
__device__ __forceinline__ float frcp_(float x) { return __builtin_amdgcn_rcpf(x); }
__device__ __forceinline__ float tanh_f(float x) {
    if (x < 0.01f) return x * (1.f - 0.33333334f * x * x);
    return 1.f - 2.f * frcp_(__expf(2.f * x) + 1.f);
}
__device__ __forceinline__ float artanh_f(float x) {
    x = fminf(x, CLIP_);
    if (x < 0.01f) return x * (1.f + 0.33333334f * x * x);
    return 0.5f * __logf((1.f + x) * frcp_(1.f - x));
}

// -------- norm-carrying mobius primitives (wave owns 256-vec, 4/lane) --------
__device__ __forceinline__ float wsum4(const float* v) {
    float ss = 0.f;
#pragma unroll
    for (int q = 0; q < 4; ++q) ss = fmaf(v[q], v[q], ss);
    return wred(ss);
}
__device__ __forceinline__ float mvf_n(float* v, float xn_raw) {
    float n = fmaxf(sqrtf(fmaxf(wsum4(v), 1e-15f)), EPS_);
    float xc = fmaxf(xn_raw, EPS_);
    float tt = tanh_f(n * frcp_(xc) * artanh_f(xc));
    float sc = tt * frcp_(n);
    float outn = tt;
    if (tt > MAXN_) { sc = MAXN_ * frcp_(n); outn = MAXN_; }
#pragma unroll
    for (int q = 0; q < 4; ++q) v[q] *= sc;
    return outn;
}
__device__ __forceinline__ float madd_n(float* x, const float* y, float x2, float y2) {
    float xy = 0.f;
#pragma unroll
    for (int q = 0; q < 4; ++q) xy = fmaf(x[q], y[q], xy);
    xy = wred(xy);
    float den = fmaxf(1.f + 2.f * xy + x2 * y2, EPS_);
    float cx = 1.f + 2.f * xy + y2, cy = 1.f - x2;
#pragma unroll
    for (int q = 0; q < 4; ++q) x[q] = cx * x[q] + cy * y[q];
    float nn = fmaf(cx * cx, x2, fmaf(2.f * cx * cy, xy, cy * cy * y2));
    float inv = frcp_(den);
    float pn = sqrtf(fmaxf(nn, 1e-15f)) * inv;
    float s = inv, outn = pn;
    if (pn > MAXN_) { s *= MAXN_ * frcp_(pn); outn = MAXN_; }
#pragma unroll
    for (int q = 0; q < 4; ++q) x[q] *= s;
    return outn;
}
__device__ __forceinline__ void lsig_n(float* v, float n_raw) {
    float nc = fmaxf(n_raw, EPS_);
    float s = artanh_f(nc) * frcp_(nc);
#pragma unroll
    for (int q = 0; q < 4; ++q) v[q] = frcp_(1.f + __expf(-v[q] * s));
}
__device__ __forceinline__ float pmul_n(const float* w, const float* x, float* o, float xn_raw) {
    float xc = fmaxf(xn_raw, EPS_);
#pragma unroll
    for (int q = 0; q < 4; ++q) o[q] = w[q] * x[q];
    float wxn = fmaxf(sqrtf(fmaxf(wsum4(o), 1e-15f)), EPS_);
    float tt = tanh_f(wxn * frcp_(xc) * artanh_f(xc));
    float sc = tt * frcp_(wxn);
    float outn = tt;
    if (tt > MAXN_) { sc = MAXN_ * frcp_(wxn); outn = MAXN_; }
#pragma unroll
    for (int q = 0; q < 4; ++q) o[q] *= sc;
    return outn;
}

// ---------------- prep kernels ----------------
__global__ __launch_bounds__(256) void k_bias(const float* __restrict__ eb, float* __restrict__ bv,
                                              float* __restrict__ bvn) {
    int wid = threadIdx.x >> 6, lane = threadIdx.x & 63;
    if (wid >= 3) return;
    const float* p = eb + wid * H_;
    float v0 = p[lane], v1 = p[lane + 64], v2 = p[lane + 128], v3 = p[lane + 192];
    float ss = wred(v0 * v0 + v1 * v1 + v2 * v2 + v3 * v3);
    float n = sqrtf(fmaxf(ss, 1e-15f));
    float nc = fmaxf(n, EPS_);
    float s = tanhf(nc) / nc;
    float nv = n * s;
    float fn = nv;
    if (nv > MAXN_) { s *= MAXN_ / nv; fn = MAXN_; }
    bv[wid * H_ + lane] = v0 * s;
    bv[wid * H_ + lane + 64] = v1 * s;
    bv[wid * H_ + lane + 128] = v2 * s;
    bv[wid * H_ + lane + 192] = v3 * s;
    if (lane == 0) bvn[wid] = fn;
}

__global__ __launch_bounds__(256) void k_packw(const float* __restrict__ whh, unsigned int* __restrict__ WPK) {
    int kp = blockIdx.x;
    for (int j = threadIdx.x; j < 768; j += 256) {
        float w0 = whh[(size_t)j * 256 + 2 * kp];
        float w1 = whh[(size_t)j * 256 + 2 * kp + 1];
        WPK[(size_t)kp * 768 + j] = packf16(w0, w1);
    }
}

__global__ __launch_bounds__(256) void k_cvt_bf16(const float* __restrict__ src, unsigned short* __restrict__ dst, int n4) {
    int i = blockIdx.x * 256 + threadIdx.x;
    if (i < n4) {
        float4 v = *(const float4*)&src[(size_t)i * 4];
        ushort4 o;
        o.x = f2bf_(v.x); o.y = f2bf_(v.y); o.z = f2bf_(v.z); o.w = f2bf_(v.w);
        *(ushort4*)&dst[(size_t)i * 4] = o;
    }
}

__global__ __launch_bounds__(256) void k_row_scale(const float* __restrict__ x, float* __restrict__ xs, float* __restrict__ xn) {
    int wid = threadIdx.x >> 6, lane = threadIdx.x & 63;
    int row = blockIdx.x * 4 + wid;
    const float* p = x + (size_t)row * IN_;
    float ss = 0.f;
#pragma unroll
    for (int q = 0; q < 12; ++q) { float v = p[lane + 64 * q]; ss = fmaf(v, v, ss); }
    ss = wred(ss);
    float n = sqrtf(fmaxf(ss, 1e-15f));
    float nc = fmaxf(n, EPS_);
    float s = tanhf(nc) / nc;
    float nv = n * s;
    if (nv > MAXN_) s *= MAXN_ / nv;
    if (lane == 0) { xs[row] = s; xn[row] = fmaxf(n * s, EPS_); }
}

// ---------------- fused MFMA bf16 GEMM + mobius_matvec finish (UX path) ----------------
// Tile 128(M) x 256(N); blockIdx.x = gate g (N-tile of exactly one gate's 256 cols).
// Epilogue: per (row, gate) norm via 16-lane shfl_xor reduce over the kq-group, then
// UX = acc * s * tanh(mxn/xv*artanh(xv))/mxn written directly; UXN[row*3+g] = final norm.
__global__ __launch_bounds__(256) void k_gemm_ux(
    const float* __restrict__ A, const unsigned short* __restrict__ Wbf,
    const float* __restrict__ xs, const float* __restrict__ xnb,
    float* __restrict__ UX, float* __restrict__ UXN)
{
    int wv = threadIdx.x >> 6, l = threadIdx.x & 63;
    int m0 = blockIdx.y * 128 + wv * 32;
    int g = blockIdx.x;                 // gate 0..2
    int n0 = g * 256;
    int r16 = l & 15, kq = l >> 4;
    f32x4 acc[2][16];
#pragma unroll
    for (int i = 0; i < 2; ++i)
#pragma unroll
        for (int j = 0; j < 16; ++j) acc[i][j] = (f32x4){0.f, 0.f, 0.f, 0.f};

    for (int k0 = 0; k0 < IN_; k0 += 32) {
        bf16x8 af[2];
#pragma unroll
        for (int mi = 0; mi < 2; ++mi) {
            const float* ap = A + (size_t)(m0 + mi * 16 + r16) * IN_ + k0 + kq * 8;
            float4 x0 = *(const float4*)ap;
            float4 x1 = *(const float4*)(ap + 4);
            af[mi][0] = (short)f2bf_(x0.x); af[mi][1] = (short)f2bf_(x0.y);
            af[mi][2] = (short)f2bf_(x0.z); af[mi][3] = (short)f2bf_(x0.w);
            af[mi][4] = (short)f2bf_(x1.x); af[mi][5] = (short)f2bf_(x1.y);
            af[mi][6] = (short)f2bf_(x1.z); af[mi][7] = (short)f2bf_(x1.w);
        }
#pragma unroll
        for (int nj = 0; nj < 16; ++nj) {
            bf16x8 bf = *(const bf16x8*)(Wbf + (size_t)(n0 + nj * 16 + r16) * IN_ + k0 + kq * 8);
            acc[0][nj] = __builtin_amdgcn_mfma_f32_16x16x32_bf16(af[0], bf, acc[0][nj], 0, 0, 0);
            acc[1][nj] = __builtin_amdgcn_mfma_f32_16x16x32_bf16(af[1], bf, acc[1][nj], 0, 0, 0);
        }
    }
    // ---- fused mobius_matvec finish ----
#pragma unroll
    for (int mi = 0; mi < 2; ++mi)
#pragma unroll
        for (int q = 0; q < 4; ++q) {
            int row = m0 + mi * 16 + kq * 4 + q;
            float ss = 0.f;
#pragma unroll
            for (int nj = 0; nj < 16; ++nj) {
                float v = acc[mi][nj][q];
                ss = fmaf(v, v, ss);
            }
            // 16-lane group reduce (stays within the kq-group for offsets < 16)
            ss += __shfl_xor(ss, 1, 64);
            ss += __shfl_xor(ss, 2, 64);
            ss += __shfl_xor(ss, 4, 64);
            ss += __shfl_xor(ss, 8, 64);
            float s = xs[row], xv = xnb[row];
            float ssc = s * s * ss;
            float mxn = fmaxf(sqrtf(fmaxf(ssc, 1e-15f)), EPS_);
            float tt = tanhf(mxn / xv * artanh_(xv));
            float sc = tt / mxn;
            float fn = tt;
            if (tt > MAXN_) { sc = MAXN_ / mxn; fn = MAXN_; }
            float tot = s * sc;
            if (r16 == 0) UXN[(size_t)row * 3 + g] = fn;
#pragma unroll
            for (int nj = 0; nj < 16; ++nj)
                UX[(size_t)row * IN_ + n0 + nj * 16 + r16] = acc[mi][nj][q] * tot;
        }
}

// ---------------- general MFMA bf16 GEMM (128-N tile): C = A @ Wbf^T (+bias)(+relu) ----------------
__global__ __launch_bounds__(256) void k_gemm_mfma_g(
    const float* __restrict__ A, int lda,
    const unsigned short* __restrict__ Wbf,
    const float* __restrict__ bias,
    float* __restrict__ C, int N, int K, int act)
{
    int wv = threadIdx.x >> 6, l = threadIdx.x & 63;
    int m0 = blockIdx.y * 128 + wv * 32;
    int n0 = blockIdx.x * 128;
    int r16 = l & 15, kq = l >> 4;
    f32x4 acc[2][8];
#pragma unroll
    for (int i = 0; i < 2; ++i)
#pragma unroll
        for (int j = 0; j < 8; ++j) acc[i][j] = (f32x4){0.f, 0.f, 0.f, 0.f};

    for (int k0 = 0; k0 < K; k0 += 32) {
        bf16x8 af[2];
#pragma unroll
        for (int mi = 0; mi < 2; ++mi) {
            const float* ap = A + (size_t)(m0 + mi * 16 + r16) * lda + k0 + kq * 8;
            float4 x0 = *(const float4*)ap;
            float4 x1 = *(const float4*)(ap + 4);
            af[mi][0] = (short)f2bf_(x0.x); af[mi][1] = (short)f2bf_(x0.y);
            af[mi][2] = (short)f2bf_(x0.z); af[mi][3] = (short)f2bf_(x0.w);
            af[mi][4] = (short)f2bf_(x1.x); af[mi][5] = (short)f2bf_(x1.y);
            af[mi][6] = (short)f2bf_(x1.z); af[mi][7] = (short)f2bf_(x1.w);
        }
#pragma unroll
        for (int nj = 0; nj < 8; ++nj) {
            bf16x8 bf = *(const bf16x8*)(Wbf + (size_t)(n0 + nj * 16 + r16) * K + k0 + kq * 8);
            acc[0][nj] = __builtin_amdgcn_mfma_f32_16x16x32_bf16(af[0], bf, acc[0][nj], 0, 0, 0);
            acc[1][nj] = __builtin_amdgcn_mfma_f32_16x16x32_bf16(af[1], bf, acc[1][nj], 0, 0, 0);
        }
    }
#pragma unroll
    for (int mi = 0; mi < 2; ++mi)
#pragma unroll
        for (int nj = 0; nj < 8; ++nj) {
            int col = n0 + nj * 16 + r16;
            float bb = bias ? bias[col] : 0.f;
#pragma unroll
            for (int q = 0; q < 4; ++q) {
                float v = acc[mi][nj][q] + bb;
                if (act) v = fmaxf(v, 0.f);
                C[(size_t)(m0 + mi * 16 + kq * 4 + q) * N + col] = v;
            }
        }
}

// ---------------- mobius GRU encoder v11 (R11 exact) ----------------
__global__ __launch_bounds__(512) void k_encoder(
    const float* __restrict__ UX, const unsigned int* __restrict__ WPK,
    const float* __restrict__ bv, const float* __restrict__ bvn,
    const float* __restrict__ UXN, float* __restrict__ Hfull)
{
    __shared__ __align__(16) unsigned int h16u[2][128];
    __shared__ __align__(16) unsigned int c16u[2][128];
    __shared__ float P1[2][512];
    __shared__ float P2[2][2][256];
    __shared__ float bias_s[3][256];
    __shared__ float zbuf[2][256];
    __shared__ float hns[2];

    int tid = threadIdx.x;
    int wid = tid >> 6, lane = tid & 63;
    int b0 = blockIdx.x * 2;

    for (int i = tid; i < 768; i += 512) bias_s[i >> 8][i & 255] = bv[i];
    if (tid < 256) h16u[tid >> 7][tid & 127] = 0u;
    if (tid < 2) hns[tid] = 0.f;
    __syncthreads();

    float bn0 = bvn[0], bn1 = bvn[1], bn2 = bvn[2];

    int j1 = (tid < 256) ? tid : (tid + 256);
    unsigned int wA[128];
#pragma unroll
    for (int kp = 0; kp < 128; ++kp) wA[kp] = WPK[(size_t)kp * 768 + j1];
    int j2i = tid & 255;
    int half = tid >> 8;
    int kb2 = half * 64;
    unsigned int wB[64];
#pragma unroll
    for (int i = 0; i < 64; ++i) wB[i] = WPK[(size_t)(kb2 + i) * 768 + 256 + j2i];

    float hreg[4] = {0.f, 0.f, 0.f, 0.f};
    float hn_c = 0.f;
    float rhn_c = 0.f;

    for (int t = 0; t < T_; ++t) {
        float uxp_a[4], uxp_b[4];
        float uxn_a = 0.f, uxn_b = 0.f;
        if (wid < 2) {
            const float* uxr = UX + ((size_t)(b0 + wid) * T_ + t) * IN_;
            float4 u0 = *(const float4*)&uxr[4 * lane];
            float4 u1 = *(const float4*)&uxr[256 + 4 * lane];
            uxp_a[0] = u0.x; uxp_a[1] = u0.y; uxp_a[2] = u0.z; uxp_a[3] = u0.w;
            uxp_b[0] = u1.x; uxp_b[1] = u1.y; uxp_b[2] = u1.z; uxp_b[3] = u1.w;
            const float* uxnp = UXN + ((size_t)(b0 + wid) * T_ + t) * 3;
            uxn_a = uxnp[0]; uxn_b = uxnp[1];
        } else if (wid < 4) {
            int row = wid - 2;
            const float* uxr = UX + ((size_t)(b0 + row) * T_ + t) * IN_;
            float4 u2 = *(const float4*)&uxr[512 + 4 * lane];
            uxp_a[0] = u2.x; uxp_a[1] = u2.y; uxp_a[2] = u2.z; uxp_a[3] = u2.w;
            uxn_a = UXN[((size_t)(b0 + row) * T_ + t) * 3 + 2];
        }

        {
            float a0 = 0.f, a1 = 0.f;
#pragma unroll
            for (int q = 0; q < 32; ++q) {
                uint4 hv0 = *(const uint4*)&h16u[0][q * 4];
                uint4 hv1 = *(const uint4*)&h16u[1][q * 4];
                a0 = dot2_(wA[q * 4 + 0], hv0.x, a0);
                a0 = dot2_(wA[q * 4 + 1], hv0.y, a0);
                a0 = dot2_(wA[q * 4 + 2], hv0.z, a0);
                a0 = dot2_(wA[q * 4 + 3], hv0.w, a0);
                a1 = dot2_(wA[q * 4 + 0], hv1.x, a1);
                a1 = dot2_(wA[q * 4 + 1], hv1.y, a1);
                a1 = dot2_(wA[q * 4 + 2], hv1.z, a1);
                a1 = dot2_(wA[q * 4 + 3], hv1.w, a1);
            }
            P1[0][tid] = a0;
            P1[1][tid] = a1;
        }
        __syncthreads();

        if (wid < 2) {
            int row = wid;
            float rr[4], tmp[4];
            float4 pr = *(const float4*)&P1[row][4 * lane];
            rr[0] = pr.x; rr[1] = pr.y; rr[2] = pr.z; rr[3] = pr.w;
            float rn = mvf_n(rr, hn_c);
            float n1 = madd_n(rr, uxp_a, rn * rn, uxn_a * uxn_a);
            {
                float4 br = *(const float4*)&bias_s[0][4 * lane];
                tmp[0] = br.x; tmp[1] = br.y; tmp[2] = br.z; tmp[3] = br.w;
            }
            float n2 = madd_n(rr, tmp, n1 * n1, bn0 * bn0);
            lsig_n(rr, n2);
            float rh[4];
            rhn_c = pmul_n(rr, hreg, rh, hn_c);
            c16u[row][2 * lane]     = packf16(rh[0], rh[1]);
            c16u[row][2 * lane + 1] = packf16(rh[2], rh[3]);
        } else if (wid < 4) {
            int row = wid - 2;
            float zr[4], tmp[4];
            float4 pz = *(const float4*)&P1[row][256 + 4 * lane];
            zr[0] = pz.x; zr[1] = pz.y; zr[2] = pz.z; zr[3] = pz.w;
            float hn_l = hns[row];
            float zn = mvf_n(zr, hn_l);
            float n1 = madd_n(zr, uxp_a, zn * zn, uxn_a * uxn_a);
            {
                float4 bz = *(const float4*)&bias_s[2][4 * lane];
                tmp[0] = bz.x; tmp[1] = bz.y; tmp[2] = bz.z; tmp[3] = bz.w;
            }
            float n2 = madd_n(zr, tmp, n1 * n1, bn2 * bn2);
            lsig_n(zr, n2);
            *(float4*)&zbuf[row][4 * lane] = make_float4(zr[0], zr[1], zr[2], zr[3]);
        }
        __syncthreads();

        {
            float c0 = 0.f, c1 = 0.f;
#pragma unroll
            for (int q = 0; q < 16; ++q) {
                uint4 cv0 = *(const uint4*)&c16u[0][kb2 + q * 4];
                uint4 cv1 = *(const uint4*)&c16u[1][kb2 + q * 4];
                c0 = dot2_(wB[q * 4 + 0], cv0.x, c0);
                c0 = dot2_(wB[q * 4 + 1], cv0.y, c0);
                c0 = dot2_(wB[q * 4 + 2], cv0.z, c0);
                c0 = dot2_(wB[q * 4 + 3], cv0.w, c0);
                c1 = dot2_(wB[q * 4 + 0], cv1.x, c1);
                c1 = dot2_(wB[q * 4 + 1], cv1.y, c1);
                c1 = dot2_(wB[q * 4 + 2], cv1.z, c1);
                c1 = dot2_(wB[q * 4 + 3], cv1.w, c1);
            }
            P2[half][0][j2i] = c0;
            P2[half][1][j2i] = c1;
        }
        __syncthreads();

        if (wid < 2) {
            int row = wid;
            float ht[4], tmp[4];
            float4 p0 = *(const float4*)&P2[0][row][4 * lane];
            float4 p1 = *(const float4*)&P2[1][row][4 * lane];
            ht[0] = p0.x + p1.x; ht[1] = p0.y + p1.y;
            ht[2] = p0.z + p1.z; ht[3] = p0.w + p1.w;
            float htn = mvf_n(ht, rhn_c);
            float n1 = madd_n(ht, uxp_b, htn * htn, uxn_b * uxn_b);
            {
                float4 bh = *(const float4*)&bias_s[1][4 * lane];
                tmp[0] = bh.x; tmp[1] = bh.y; tmp[2] = bh.z; tmp[3] = bh.w;
            }
            float n2 = madd_n(ht, tmp, n1 * n1, bn1 * bn1);
            float dl[4];
#pragma unroll
            for (int q = 0; q < 4; ++q) dl[q] = -hreg[q];
            float dn = madd_n(dl, ht, hn_c * hn_c, n2 * n2);
            float zv[4];
            {
                float4 zl = *(const float4*)&zbuf[row][4 * lane];
                zv[0] = zl.x; zv[1] = zl.y; zv[2] = zl.z; zv[3] = zl.w;
            }
            float dv[4];
            float dvn = pmul_n(zv, dl, dv, dn);
            float hn_new = madd_n(hreg, dv, hn_c * hn_c, dvn * dvn);
            hn_c = hn_new;
            float ncl = fmaxf(hn_new, EPS_);
            float ls = artanh_f(ncl) * frcp_(ncl);
            float* orow = Hfull + ((size_t)(b0 + row) * T_ + t) * H_;
            *(float4*)&orow[4 * lane] = make_float4(hreg[0] * ls, hreg[1] * ls, hreg[2] * ls, hreg[3] * ls);
            h16u[row][2 * lane]     = packf16(hreg[0], hreg[1]);
            h16u[row][2 * lane + 1] = packf16(hreg[2], hreg[3]);
            if (lane == 0) hns[row] = hn_new;
        }
        __syncthreads();
    }
}

// score[b,t] = v . tanh(S1 + b1 + q[b]) + bv, masked
__global__ __launch_bounds__(256) void k_score(
    const float* __restrict__ S1, const float* __restrict__ q,
    const float* __restrict__ b1, const float* __restrict__ av,
    const float* __restrict__ abv, const int* __restrict__ len,
    float* __restrict__ sc)
{
    int wid = threadIdx.x >> 6, lane = threadIdx.x & 63;
    int row = blockIdx.x * 4 + wid;
    int b = row / T_, t = row - b * T_;
    const float* s1 = S1 + (size_t)row * H_;
    const float* qp = q + (size_t)b * H_;
    float part = 0.f;
#pragma unroll
    for (int qq = 0; qq < 4; ++qq) {
        int j = lane + 64 * qq;
        float u = tanhf(s1[j] + b1[j] + qp[j]);
        part = fmaf(u, av[j], part);
    }
    part = wred(part) + abv[0];
    if (t >= len[b]) part = -1e9f;
    if (lane == 0) sc[row] = part;
}

// per-b: softmax over T, ctx = sum w*full, span logits + softmax -> d_out
__global__ __launch_bounds__(256) void k_ctx(
    const float* __restrict__ sc, const float* __restrict__ full,
    const float* __restrict__ spw, const float* __restrict__ spb,
    float* __restrict__ ctx, float* __restrict__ outsp)
{
    int b = blockIdx.x, tid = threadIdx.x;
    __shared__ float w_s[T_];
    __shared__ float cs[H_];
    __shared__ float red[NSPAN];
    if (tid < T_) w_s[tid] = sc[b * T_ + tid];
    __syncthreads();
    if (tid == 0) {
        float mx = -1e30f;
        for (int t = 0; t < T_; ++t) mx = fmaxf(mx, w_s[t]);
        float sum = 0.f;
        for (int t = 0; t < T_; ++t) { float e = expf(w_s[t] - mx); w_s[t] = e; sum += e; }
        float inv = 1.f / sum;
        for (int t = 0; t < T_; ++t) w_s[t] *= inv;
    }
    __syncthreads();
    float c = 0.f;
    for (int t = 0; t < T_; ++t) c = fmaf(w_s[t], full[((size_t)b * T_ + t) * H_ + tid], c);
    ctx[(size_t)b * H_ + tid] = c;
    cs[tid] = c;
    __syncthreads();
    if (tid < NSPAN) {
        float lg = spb[tid];
        for (int j = 0; j < H_; ++j) lg = fmaf(spw[tid * H_ + j], cs[j], lg);
        red[tid] = lg;
    }
    __syncthreads();
    if (tid == 0) {
        float mx = red[0];
        for (int k2 = 1; k2 < NSPAN; ++k2) mx = fmaxf(mx, red[k2]);
        float sum = 0.f;
        for (int k2 = 0; k2 < NSPAN; ++k2) sum += expf(red[k2] - mx);
        float inv = 1.f / sum;
        for (int k2 = 0; k2 < NSPAN; ++k2) outsp[(size_t)b * NSPAN + k2] = expf(red[k2] - mx) * inv;
    }
}

// ---------------- decoder v2 (R18 exact): LDS-staged weights, gate-aligned wave columns ----------------
#define WBS 40   // padded chunk row stride in ushorts (32 used + 8 pad; 80B, 16B-aligned)
__device__ __forceinline__ void dec_gemm(
    const unsigned short* __restrict__ W, int K, int NCH,
    const unsigned short* As, int ast,
    unsigned short* Wb0, unsigned short* Wb1,
    f32x4 acc[6], const int nb[6],
    int tid, int r16, int kq)
{
    uint4 regs[6];
#pragma unroll
    for (int r = 0; r < 6; ++r) {
        int task = tid + r * 512, n = task >> 2, sub = task & 3;
        regs[r] = *(const uint4*)&W[(size_t)n * K + sub * 8];
    }
#pragma unroll
    for (int r = 0; r < 6; ++r) {
        int task = tid + r * 512, n = task >> 2, sub = task & 3;
        *(uint4*)&Wb0[n * WBS + sub * 8] = regs[r];
    }
    __syncthreads();
    for (int c = 0; c < NCH; ++c) {
        unsigned short* cur = (c & 1) ? Wb1 : Wb0;
        unsigned short* nxt = (c & 1) ? Wb0 : Wb1;
        if (c + 1 < NCH) {
#pragma unroll
            for (int r = 0; r < 6; ++r) {
                int task = tid + r * 512, n = task >> 2, sub = task & 3;
                regs[r] = *(const uint4*)&W[(size_t)n * K + (c + 1) * 32 + sub * 8];
            }
        }
        bf16x8 a = *(const bf16x8*)&As[r16 * ast + c * 32 + kq * 8];
#pragma unroll
        for (int f = 0; f < 6; ++f) {
            bf16x8 b = *(const bf16x8*)&cur[(nb[f] + r16) * WBS + kq * 8];
            acc[f] = __builtin_amdgcn_mfma_f32_16x16x32_bf16(a, b, acc[f], 0, 0, 0);
        }
        if (c + 1 < NCH) {
#pragma unroll
            for (int r = 0; r < 6; ++r) {
                int task = tid + r * 512, n = task >> 2, sub = task & 3;
                *(uint4*)&nxt[n * WBS + sub * 8] = regs[r];
            }
        }
        __syncthreads();
    }
}

__global__ __launch_bounds__(512) void k_decoder(
    const float* __restrict__ ctx,
    const unsigned short* __restrict__ Wih,   // (768,768) bf16
    const unsigned short* __restrict__ Whh,   // (768,256) bf16
    const unsigned short* __restrict__ Wfc,   // (768,256) bf16
    const float* __restrict__ b_ih, const float* __restrict__ b_hh,
    const float* __restrict__ b_fc,
    const float* __restrict__ fow, const float* __restrict__ fob,
    float* __restrict__ outp)
{
    __shared__ __align__(16) unsigned short Wb[2][768 * WBS];  // 120 KB
    __shared__ __align__(16) unsigned short inp16[16][776];    // 24.25 KB
    __shared__ __align__(16) unsigned short h16d[16][264];     // 8.25 KB
    __shared__ float red_s[8][16][2];                          // 1 KB

    int tid = threadIdx.x;
    int wv = tid >> 6, l = tid & 63;
    int r0 = blockIdx.x * 16;
    int r16 = l & 15, kq = l >> 4;

    int nbg[6], nbf[6];
    float bih[6], bhh[6], bfc6[6];
#pragma unroll
    for (int f = 0; f < 6; ++f) {
        int g = f >> 1, d = f & 1;
        nbg[f] = g * 256 + wv * 32 + d * 16;
        bih[f] = b_ih[nbg[f] + r16];
        bhh[f] = b_hh[nbg[f] + r16];
        nbf[f] = wv * 96 + f * 16;
        bfc6[f] = b_fc[nbf[f] + r16];
    }
    float fowr[2][2];
#pragma unroll
    for (int o = 0; o < 2; ++o)
#pragma unroll
        for (int d = 0; d < 2; ++d) fowr[o][d] = fow[o * 256 + wv * 32 + d * 16 + r16];
    float fb0 = fob[0], fb1 = fob[1];

    for (int i = tid; i < 16 * 776; i += 512) ((unsigned short*)inp16)[i] = 0;
    for (int i = tid; i < 16 * 256; i += 512) {
        int row = i >> 8, c = i & 255;
        h16d[row][c] = f2bf_(ctx[(size_t)(r0 + row) * H_ + c]);
    }
    float hreg[2][4];
#pragma unroll
    for (int d = 0; d < 2; ++d)
#pragma unroll
        for (int q = 0; q < 4; ++q)
            hreg[d][q] = ctx[(size_t)(r0 + kq * 4 + q) * H_ + wv * 32 + d * 16 + r16];
    __syncthreads();

    for (int t = 0; t < NDAYS; ++t) {
        // ---- gi / gh GEMMs ----
        f32x4 gacc[6], hacc[6];
#pragma unroll
        for (int f = 0; f < 6; ++f) { gacc[f] = (f32x4){0.f,0.f,0.f,0.f}; hacc[f] = (f32x4){0.f,0.f,0.f,0.f}; }
        // t=0: inp == 0 -> gi is bias-only; skip the 24-chunk gi GEMM entirely.
        if (t > 0)
            dec_gemm(Wih, 768, 24, &inp16[0][0], 776, Wb[0], Wb[1], gacc, nbg, tid, r16, kq);
        dec_gemm(Whh, 256,  8, &h16d[0][0], 264, Wb[0], Wb[1], hacc, nbg, tid, r16, kq);
        // ---- GRU cell (lane-local) ----
#pragma unroll
        for (int d = 0; d < 2; ++d)
#pragma unroll
            for (int q = 0; q < 4; ++q) {
                float rr = frcp_(1.f + __expf(-(gacc[d][q] + bih[d] + hacc[d][q] + bhh[d])));
                float zz = frcp_(1.f + __expf(-(gacc[2 + d][q] + bih[2 + d] + hacc[2 + d][q] + bhh[2 + d])));
                float nn = tanhf(fmaf(rr, hacc[4 + d][q] + bhh[4 + d], gacc[4 + d][q] + bih[4 + d]));
                float hnew = (1.f - zz) * nn + zz * hreg[d][q];
                hreg[d][q] = hnew;
                h16d[kq * 4 + q][wv * 32 + d * 16 + r16] = f2bf_(hnew);
            }
        __syncthreads();
        // ---- inp' = relu(h @ Wfc^T + b_fc) ----
        if (t + 1 < NDAYS) {
            f32x4 iacc[6];
#pragma unroll
            for (int f = 0; f < 6; ++f) iacc[f] = (f32x4){0.f,0.f,0.f,0.f};
            dec_gemm(Wfc, 256, 8, &h16d[0][0], 264, Wb[0], Wb[1], iacc, nbf, tid, r16, kq);
#pragma unroll
            for (int f = 0; f < 6; ++f)
#pragma unroll
                for (int q = 0; q < 4; ++q)
                    inp16[kq * 4 + q][nbf[f] + r16] = f2bf_(fmaxf(iacc[f][q] + bfc6[f], 0.f));
        }
        // ---- fc_out: per-wave partials over its 32 cols, LDS reduce ----
        {
            float pq[2][4];
#pragma unroll
            for (int o = 0; o < 2; ++o)
#pragma unroll
                for (int q = 0; q < 4; ++q)
                    pq[o][q] = fmaf(hreg[0][q], fowr[o][0], hreg[1][q] * fowr[o][1]);
#pragma unroll
            for (int o = 0; o < 2; ++o)
#pragma unroll
                for (int q = 0; q < 4; ++q) {
                    float v = pq[o][q];
                    v += __shfl_xor(v, 1, 64); v += __shfl_xor(v, 2, 64);
                    v += __shfl_xor(v, 4, 64); v += __shfl_xor(v, 8, 64);
                    pq[o][q] = v;
                }
            if (r16 == 0) {
#pragma unroll
                for (int q = 0; q < 4; ++q) {
                    red_s[wv][kq * 4 + q][0] = pq[0][q];
                    red_s[wv][kq * 4 + q][1] = pq[1][q];
                }
            }
        }
        __syncthreads();
        if (tid < 16) {
            float l0 = fb0, l1 = fb1;
#pragma unroll
            for (int w = 0; w < 8; ++w) { l0 += red_s[w][tid][0]; l1 += red_s[w][tid][1]; }
            float mx = fmaxf(l0, l1);
            float e0 = __expf(l0 - mx), e1 = __expf(l1 - mx);
            float inv = frcp_(e0 + e1);
            float* op = outp + (size_t)(r0 + tid) * (NDAYS * OUTD) + t * OUTD;
            op[0] = e0 * inv; op[1] = e1 * inv;
        }
        __syncthreads();
    }
}

extern "C" void kernel_launch(void* const* d_in, const int* in_sizes, int n_in,
                              void* d_out, int out_size, void* d_ws, size_t ws_size,
                              hipStream_t stream)
{
    (void)in_sizes; (void)n_in; (void)out_size; (void)ws_size;
    const float* x        = (const float*)d_in[0];
    const int*   len      = (const int*)  d_in[1];
    const float* enc_w_ih = (const float*)d_in[2];
    const float* enc_w_hh = (const float*)d_in[3];
    const float* enc_bias = (const float*)d_in[4];
    const float* dec_w_ih = (const float*)d_in[5];
    const float* dec_w_hh = (const float*)d_in[6];
    const float* dec_b_ih = (const float*)d_in[7];
    const float* dec_b_hh = (const float*)d_in[8];
    const float* attn_w1  = (const float*)d_in[9];
    const float* attn_b1  = (const float*)d_in[10];
    const float* attn_w2  = (const float*)d_in[11];
    const float* attn_b2  = (const float*)d_in[12];
    const float* attn_v   = (const float*)d_in[13];
    const float* attn_bv  = (const float*)d_in[14];
    const float* fc_in_w  = (const float*)d_in[15];
    const float* fc_in_b  = (const float*)d_in[16];
    const float* fc_out_w = (const float*)d_in[17];
    const float* fc_out_b = (const float*)d_in[18];
    const float* span_w   = (const float*)d_in[19];
    const float* span_b   = (const float*)d_in[20];
    float* out = (float*)d_out;
    float* wsf = (float*)d_ws;

    const size_t ROWS = (size_t)B_ * T_;            // 38400
    float* UX    = wsf;                             // 38400*768
    float* Hfull = UX + ROWS * IN_;                 // 38400*256
    float* xs    = Hfull + ROWS * H_;               // 38400
    float* xnb   = xs + ROWS;                       // 38400
    float* WT    = xnb + ROWS;                      // 256*768 floats (packed enc weights)
    float* bvv   = WT + 256 * 768;                  // 768
    float* bvn   = bvv + 768;                       // 16 (3 used)
    float* UXN   = bvn + 16;                        // 38400*3
    float* qbuf  = UXN + ROWS * 3;                  // 512*256
    float* scb   = qbuf + (size_t)B_ * H_;          // 38400
    float* ctx   = scb + ROWS;                      // 512*256
    float* wpool = ctx + (size_t)B_ * H_;           // bf16 weight pool
    unsigned int* WPK = (unsigned int*)WT;
    unsigned short* Wencbf = (unsigned short*)wpool;                 // 768*768
    unsigned short* W1bf   = Wencbf + (size_t)768 * 768;             // 256*256
    unsigned short* W2bf   = W1bf + (size_t)256 * 256;               // 256*256
    unsigned short* DWIHbf = W2bf + (size_t)256 * 256;               // 768*768
    unsigned short* DWHHbf = DWIHbf + (size_t)768 * 768;             // 768*256
    unsigned short* FCINbf = DWHHbf + (size_t)768 * 256;             // 768*256
    float* S1 = UX;   // reuse after encoder consumes UX

    k_bias<<<1, 256, 0, stream>>>(enc_bias, bvv, bvn);
    k_packw<<<128, 256, 0, stream>>>(enc_w_hh, WPK);
    k_cvt_bf16<<<576, 256, 0, stream>>>(enc_w_ih, Wencbf, 768 * 768 / 4);
    k_cvt_bf16<<<64, 256, 0, stream>>>(attn_w1, W1bf, 256 * 256 / 4);
    k_cvt_bf16<<<64, 256, 0, stream>>>(attn_w2, W2bf, 256 * 256 / 4);
    k_cvt_bf16<<<576, 256, 0, stream>>>(dec_w_ih, DWIHbf, 768 * 768 / 4);
    k_cvt_bf16<<<192, 256, 0, stream>>>(dec_w_hh, DWHHbf, 768 * 256 / 4);
    k_cvt_bf16<<<192, 256, 0, stream>>>(fc_in_w, FCINbf, 768 * 256 / 4);
    k_row_scale<<<(unsigned)(ROWS / 4), 256, 0, stream>>>(x, xs, xnb);
    // fused GEMM + mobius_matvec finish: writes UX (scaled) and UXN directly
    k_gemm_ux<<<dim3(3, (unsigned)(ROWS / 128)), 256, 0, stream>>>(x, Wencbf, xs, xnb, UX, UXN);
    k_encoder<<<B_ / 2, 512, 0, stream>>>(UX, WPK, bvv, bvn, UXN, Hfull);
    // Hfull is already logmapped. q = hx @ w2^T + b2 (hx = rows t=T-1, stride T*H)
    k_gemm_mfma_g<<<dim3(H_ / 128, B_ / 128), 256, 0, stream>>>(Hfull + (T_ - 1) * H_, T_ * H_, W2bf, attn_b2, qbuf, H_, H_, 0);
    k_gemm_mfma_g<<<dim3(H_ / 128, (unsigned)(ROWS / 128)), 256, 0, stream>>>(Hfull, H_, W1bf, nullptr, S1, H_, H_, 0);
    k_score<<<(unsigned)(ROWS / 4), 256, 0, stream>>>(S1, qbuf, attn_b1, attn_v, attn_bv, len, scb);
    k_ctx<<<B_, 256, 0, stream>>>(scb, Hfull, span_w, span_b, ctx, out);
    k_decoder<<<B_ / 16, 512, 0, stream>>>(ctx, DWIHbf, DWHHbf, FCINbf,
                                           dec_b_ih, dec_b_hh, fc_in_b,
                                           fc_out_w, fc_out_b, out + B_ * NSPAN);
}

// Round 20
// 1360.425 us; speedup vs baseline: 1.0643x; 1.0643x over previous
//
#include <hip/hip_runtime.h>
#include <hip/hip_fp16.h>
#include <math.h>

#define B_    512
#define T_    75
#define IN_   768
#define H_    256
#define NSPAN 8
#define OUTD  2
#define NDAYS 10
#define EPS_  1e-5f
#define MAXN_ 0.999f
#define CLIP_ (1.0f - 1e-7f)

typedef short bf16x8 __attribute__((ext_vector_type(8)));
typedef float f32x4 __attribute__((ext_vector_type(4)));

// ---------------- wave helpers (wave = 64 lanes) ----------------
// DPP-based wave reduction: VALU pipe instead of ds_swizzle.
template<int CTRL, int RMASK>
__device__ __forceinline__ float dppadd_(float v) {
    return v + __int_as_float(__builtin_amdgcn_update_dpp(
        0, __float_as_int(v), CTRL, RMASK, 0xf, true));
}
__device__ __forceinline__ float wred(float v) {
    v = dppadd_<0x111, 0xf>(v);   // row_shr:1
    v = dppadd_<0x112, 0xf>(v);   // row_shr:2
    v = dppadd_<0x114, 0xf>(v);   // row_shr:4
    v = dppadd_<0x118, 0xf>(v);   // row_shr:8
    v = dppadd_<0x142, 0xa>(v);   // row_bcast:15
    v = dppadd_<0x143, 0xc>(v);   // row_bcast:31; lane63 = total
    return __int_as_float(__builtin_amdgcn_readlane(__float_as_int(v), 63));
}
__device__ __forceinline__ float artanh_(float x) {
    x = fminf(x, CLIP_);
    return 0.5f * logf((1.f + x) / (1.f - x));
}
__device__ __forceinline__ float sigm_(float x) { return 1.f / (1.f + expf(-x)); }
__device__ __forceinline__ float h2f_(unsigned short u) {
    union { unsigned short us; __half h; } cv; cv.us = u;
    return __half2float(cv.h);
}
__device__ __forceinline__ unsigned int packf16(float a, float b) {
    union { __half h; unsigned short us; } ca, cb;
    ca.h = __float2half(a); cb.h = __float2half(b);
    return (unsigned int)ca.us | ((unsigned int)cb.us << 16);
}
__device__ __forceinline__ unsigned short f2bf_(float f) {  // RNE f32->bf16
    union { float f; unsigned u; } c; c.f = f;
    unsigned r = c.u + 0x7fff + ((c.u >> 16) & 1);
    return (unsigned short)(r >> 16);
}
// f16-pair dot product with f32 accumulator
__device__ __forceinline__ float dot2_(unsigned int w, unsigned int h, float acc) {
#if __has_builtin(__builtin_amdgcn_fdot2)
    typedef _Float16 h2_t __attribute__((ext_vector_type(2)));
    union { unsigned int u; h2_t v; } a, b;
    a.u = w; b.u = h;
    return __builtin_amdgcn_fdot2(a.v, b.v, acc, false);
#else
    float wx = h2f_((unsigned short)(w & 0xffff)), wy = h2f_((unsigned short)(w >> 16));
    float hx = h2f_((unsigned short)(h & 0xffff)), hy = h2f_((unsigned short)(h >> 16));
    return fmaf(wy, hy, fmaf(wx, hx, acc));
#endif
}
// ---- fast-math (encoder hot path). Args are wave-uniform norms >= 0. ----
__device__ __forceinline__ float frcp_(float x) { return __builtin_amdgcn_rcpf(x); }
__device__ __forceinline__ float tanh_f(float x) {
    if (x < 0.01f) return x * (1.f - 0.33333334f * x * x);
    return 1.f - 2.f * frcp_(__expf(2.f * x) + 1.f);
}
__device__ __forceinline__ float artanh_f(float x) {
    x = fminf(x, CLIP_);
    if (x < 0.01f) return x * (1.f + 0.33333334f * x * x);
    return 0.5f * __logf((1.f + x) * frcp_(1.f - x));
}

// -------- norm-carrying mobius primitives (wave owns 256-vec, 4/lane) --------
__device__ __forceinline__ float wsum4(const float* v) {
    float ss = 0.f;
#pragma unroll
    for (int q = 0; q < 4; ++q) ss = fmaf(v[q], v[q], ss);
    return wred(ss);
}
__device__ __forceinline__ float mvf_n(float* v, float xn_raw) {
    float n = fmaxf(sqrtf(fmaxf(wsum4(v), 1e-15f)), EPS_);
    float xc = fmaxf(xn_raw, EPS_);
    float tt = tanh_f(n * frcp_(xc) * artanh_f(xc));
    float sc = tt * frcp_(n);
    float outn = tt;
    if (tt > MAXN_) { sc = MAXN_ * frcp_(n); outn = MAXN_; }
#pragma unroll
    for (int q = 0; q < 4; ++q) v[q] *= sc;
    return outn;
}
__device__ __forceinline__ float madd_n(float* x, const float* y, float x2, float y2) {
    float xy = 0.f;
#pragma unroll
    for (int q = 0; q < 4; ++q) xy = fmaf(x[q], y[q], xy);
    xy = wred(xy);
    float den = fmaxf(1.f + 2.f * xy + x2 * y2, EPS_);
    float cx = 1.f + 2.f * xy + y2, cy = 1.f - x2;
#pragma unroll
    for (int q = 0; q < 4; ++q) x[q] = cx * x[q] + cy * y[q];
    float nn = fmaf(cx * cx, x2, fmaf(2.f * cx * cy, xy, cy * cy * y2));
    float inv = frcp_(den);
    float pn = sqrtf(fmaxf(nn, 1e-15f)) * inv;
    float s = inv, outn = pn;
    if (pn > MAXN_) { s *= MAXN_ * frcp_(pn); outn = MAXN_; }
#pragma unroll
    for (int q = 0; q < 4; ++q) x[q] *= s;
    return outn;
}
__device__ __forceinline__ void lsig_n(float* v, float n_raw) {
    float nc = fmaxf(n_raw, EPS_);
    float s = artanh_f(nc) * frcp_(nc);
#pragma unroll
    for (int q = 0; q < 4; ++q) v[q] = frcp_(1.f + __expf(-v[q] * s));
}
__device__ __forceinline__ float pmul_n(const float* w, const float* x, float* o, float xn_raw) {
    float xc = fmaxf(xn_raw, EPS_);
#pragma unroll
    for (int q = 0; q < 4; ++q) o[q] = w[q] * x[q];
    float wxn = fmaxf(sqrtf(fmaxf(wsum4(o), 1e-15f)), EPS_);
    float tt = tanh_f(wxn * frcp_(xc) * artanh_f(xc));
    float sc = tt * frcp_(wxn);
    float outn = tt;
    if (tt > MAXN_) { sc = MAXN_ * frcp_(wxn); outn = MAXN_; }
#pragma unroll
    for (int q = 0; q < 4; ++q) o[q] *= sc;
    return outn;
}

// ---------------- prep kernels ----------------
__global__ __launch_bounds__(256) void k_bias(const float* __restrict__ eb, float* __restrict__ bv,
                                              float* __restrict__ bvn) {
    int wid = threadIdx.x >> 6, lane = threadIdx.x & 63;
    if (wid >= 3) return;
    const float* p = eb + wid * H_;
    float v0 = p[lane], v1 = p[lane + 64], v2 = p[lane + 128], v3 = p[lane + 192];
    float ss = wred(v0 * v0 + v1 * v1 + v2 * v2 + v3 * v3);
    float n = sqrtf(fmaxf(ss, 1e-15f));
    float nc = fmaxf(n, EPS_);
    float s = tanhf(nc) / nc;
    float nv = n * s;
    float fn = nv;
    if (nv > MAXN_) { s *= MAXN_ / nv; fn = MAXN_; }
    bv[wid * H_ + lane] = v0 * s;
    bv[wid * H_ + lane + 64] = v1 * s;
    bv[wid * H_ + lane + 128] = v2 * s;
    bv[wid * H_ + lane + 192] = v3 * s;
    if (lane == 0) bvn[wid] = fn;
}

__global__ __launch_bounds__(256) void k_packw(const float* __restrict__ whh, unsigned int* __restrict__ WPK) {
    int kp = blockIdx.x;
    for (int j = threadIdx.x; j < 768; j += 256) {
        float w0 = whh[(size_t)j * 256 + 2 * kp];
        float w1 = whh[(size_t)j * 256 + 2 * kp + 1];
        WPK[(size_t)kp * 768 + j] = packf16(w0, w1);
    }
}

__global__ __launch_bounds__(256) void k_cvt_bf16(const float* __restrict__ src, unsigned short* __restrict__ dst, int n4) {
    int i = blockIdx.x * 256 + threadIdx.x;
    if (i < n4) {
        float4 v = *(const float4*)&src[(size_t)i * 4];
        ushort4 o;
        o.x = f2bf_(v.x); o.y = f2bf_(v.y); o.z = f2bf_(v.z); o.w = f2bf_(v.w);
        *(ushort4*)&dst[(size_t)i * 4] = o;
    }
}

__global__ __launch_bounds__(256) void k_row_scale(const float* __restrict__ x, float* __restrict__ xs, float* __restrict__ xn) {
    int wid = threadIdx.x >> 6, lane = threadIdx.x & 63;
    int row = blockIdx.x * 4 + wid;
    const float* p = x + (size_t)row * IN_;
    float ss = 0.f;
#pragma unroll
    for (int q = 0; q < 12; ++q) { float v = p[lane + 64 * q]; ss = fmaf(v, v, ss); }
    ss = wred(ss);
    float n = sqrtf(fmaxf(ss, 1e-15f));
    float nc = fmaxf(n, EPS_);
    float s = tanhf(nc) / nc;
    float nv = n * s;
    if (nv > MAXN_) s *= MAXN_ / nv;
    if (lane == 0) { xs[row] = s; xn[row] = fmaxf(n * s, EPS_); }
}

__global__ __launch_bounds__(256) void k_ux_scale(float* __restrict__ MX, const float* __restrict__ xs,
                                                  const float* __restrict__ xnb, float* __restrict__ UXN) {
    int wid = threadIdx.x >> 6, lane = threadIdx.x & 63;
    int rg = blockIdx.x * 4 + wid;
    int row = rg / 3, g = rg - row * 3;
    float s = xs[row], xv = xnb[row];
    float* p = MX + (size_t)row * IN_ + g * H_;
    float v0 = p[lane] * s, v1 = p[lane + 64] * s, v2 = p[lane + 128] * s, v3 = p[lane + 192] * s;
    float ss = wred(v0 * v0 + v1 * v1 + v2 * v2 + v3 * v3);
    float mxn = fmaxf(sqrtf(fmaxf(ss, 1e-15f)), EPS_);
    float tt = tanhf(mxn / xv * artanh_(xv));
    float sc = tt / mxn;
    float fn = tt;
    if (tt > MAXN_) { sc = MAXN_ / mxn; fn = MAXN_; }
    p[lane] = v0 * sc; p[lane + 64] = v1 * sc; p[lane + 128] = v2 * sc; p[lane + 192] = v3 * sc;
    if (lane == 0) UXN[rg] = fn;
}

// ---------------- MFMA bf16 GEMM (192-N tile, for the big UX GEMM) ----------------
__global__ __launch_bounds__(256) void k_gemm_mfma(
    const float* __restrict__ A, const unsigned short* __restrict__ Wbf,
    float* __restrict__ C, int M, int N, int K)
{
    int wv = threadIdx.x >> 6, l = threadIdx.x & 63;
    int m0 = blockIdx.y * 128 + wv * 32;
    int n0 = blockIdx.x * 192;
    int r16 = l & 15, kq = l >> 4;
    f32x4 acc[2][12];
#pragma unroll
    for (int i = 0; i < 2; ++i)
#pragma unroll
        for (int j = 0; j < 12; ++j) acc[i][j] = (f32x4){0.f, 0.f, 0.f, 0.f};

    for (int k0 = 0; k0 < K; k0 += 32) {
        bf16x8 af[2];
#pragma unroll
        for (int mi = 0; mi < 2; ++mi) {
            const float* ap = A + (size_t)(m0 + mi * 16 + r16) * K + k0 + kq * 8;
            float4 x0 = *(const float4*)ap;
            float4 x1 = *(const float4*)(ap + 4);
            af[mi][0] = (short)f2bf_(x0.x); af[mi][1] = (short)f2bf_(x0.y);
            af[mi][2] = (short)f2bf_(x0.z); af[mi][3] = (short)f2bf_(x0.w);
            af[mi][4] = (short)f2bf_(x1.x); af[mi][5] = (short)f2bf_(x1.y);
            af[mi][6] = (short)f2bf_(x1.z); af[mi][7] = (short)f2bf_(x1.w);
        }
#pragma unroll
        for (int nj = 0; nj < 12; ++nj) {
            bf16x8 bf = *(const bf16x8*)(Wbf + (size_t)(n0 + nj * 16 + r16) * K + k0 + kq * 8);
            acc[0][nj] = __builtin_amdgcn_mfma_f32_16x16x32_bf16(af[0], bf, acc[0][nj], 0, 0, 0);
            acc[1][nj] = __builtin_amdgcn_mfma_f32_16x16x32_bf16(af[1], bf, acc[1][nj], 0, 0, 0);
        }
    }
#pragma unroll
    for (int mi = 0; mi < 2; ++mi)
#pragma unroll
        for (int nj = 0; nj < 12; ++nj)
#pragma unroll
            for (int q = 0; q < 4; ++q)
                C[(size_t)(m0 + mi * 16 + kq * 4 + q) * N + n0 + nj * 16 + r16] = acc[mi][nj][q];
}

// ---------------- general MFMA bf16 GEMM (128-N tile): C = A @ Wbf^T (+bias)(+relu) ----------------
__global__ __launch_bounds__(256) void k_gemm_mfma_g(
    const float* __restrict__ A, int lda,
    const unsigned short* __restrict__ Wbf,
    const float* __restrict__ bias,
    float* __restrict__ C, int N, int K, int act)
{
    int wv = threadIdx.x >> 6, l = threadIdx.x & 63;
    int m0 = blockIdx.y * 128 + wv * 32;
    int n0 = blockIdx.x * 128;
    int r16 = l & 15, kq = l >> 4;
    f32x4 acc[2][8];
#pragma unroll
    for (int i = 0; i < 2; ++i)
#pragma unroll
        for (int j = 0; j < 8; ++j) acc[i][j] = (f32x4){0.f, 0.f, 0.f, 0.f};

    for (int k0 = 0; k0 < K; k0 += 32) {
        bf16x8 af[2];
#pragma unroll
        for (int mi = 0; mi < 2; ++mi) {
            const float* ap = A + (size_t)(m0 + mi * 16 + r16) * lda + k0 + kq * 8;
            float4 x0 = *(const float4*)ap;
            float4 x1 = *(const float4*)(ap + 4);
            af[mi][0] = (short)f2bf_(x0.x); af[mi][1] = (short)f2bf_(x0.y);
            af[mi][2] = (short)f2bf_(x0.z); af[mi][3] = (short)f2bf_(x0.w);
            af[mi][4] = (short)f2bf_(x1.x); af[mi][5] = (short)f2bf_(x1.y);
            af[mi][6] = (short)f2bf_(x1.z); af[mi][7] = (short)f2bf_(x1.w);
        }
#pragma unroll
        for (int nj = 0; nj < 8; ++nj) {
            bf16x8 bf = *(const bf16x8*)(Wbf + (size_t)(n0 + nj * 16 + r16) * K + k0 + kq * 8);
            acc[0][nj] = __builtin_amdgcn_mfma_f32_16x16x32_bf16(af[0], bf, acc[0][nj], 0, 0, 0);
            acc[1][nj] = __builtin_amdgcn_mfma_f32_16x16x32_bf16(af[1], bf, acc[1][nj], 0, 0, 0);
        }
    }
#pragma unroll
    for (int mi = 0; mi < 2; ++mi)
#pragma unroll
        for (int nj = 0; nj < 8; ++nj) {
            int col = n0 + nj * 16 + r16;
            float bb = bias ? bias[col] : 0.f;
#pragma unroll
            for (int q = 0; q < 4; ++q) {
                float v = acc[mi][nj][q] + bb;
                if (act) v = fmaxf(v, 0.f);
                C[(size_t)(m0 + mi * 16 + kq * 4 + q) * N + col] = v;
            }
        }
}

// ---------------- mobius GRU encoder v11 (R11 exact) ----------------
__global__ __launch_bounds__(512) void k_encoder(
    const float* __restrict__ UX, const unsigned int* __restrict__ WPK,
    const float* __restrict__ bv, const float* __restrict__ bvn,
    const float* __restrict__ UXN, float* __restrict__ Hfull)
{
    __shared__ __align__(16) unsigned int h16u[2][128];
    __shared__ __align__(16) unsigned int c16u[2][128];
    __shared__ float P1[2][512];
    __shared__ float P2[2][2][256];
    __shared__ float bias_s[3][256];
    __shared__ float zbuf[2][256];
    __shared__ float hns[2];

    int tid = threadIdx.x;
    int wid = tid >> 6, lane = tid & 63;
    int b0 = blockIdx.x * 2;

    for (int i = tid; i < 768; i += 512) bias_s[i >> 8][i & 255] = bv[i];
    if (tid < 256) h16u[tid >> 7][tid & 127] = 0u;
    if (tid < 2) hns[tid] = 0.f;
    __syncthreads();

    float bn0 = bvn[0], bn1 = bvn[1], bn2 = bvn[2];

    int j1 = (tid < 256) ? tid : (tid + 256);
    unsigned int wA[128];
#pragma unroll
    for (int kp = 0; kp < 128; ++kp) wA[kp] = WPK[(size_t)kp * 768 + j1];
    int j2i = tid & 255;
    int half = tid >> 8;
    int kb2 = half * 64;
    unsigned int wB[64];
#pragma unroll
    for (int i = 0; i < 64; ++i) wB[i] = WPK[(size_t)(kb2 + i) * 768 + 256 + j2i];

    float hreg[4] = {0.f, 0.f, 0.f, 0.f};
    float hn_c = 0.f;
    float rhn_c = 0.f;

    for (int t = 0; t < T_; ++t) {
        float uxp_a[4], uxp_b[4];
        float uxn_a = 0.f, uxn_b = 0.f;
        if (wid < 2) {
            const float* uxr = UX + ((size_t)(b0 + wid) * T_ + t) * IN_;
            float4 u0 = *(const float4*)&uxr[4 * lane];
            float4 u1 = *(const float4*)&uxr[256 + 4 * lane];
            uxp_a[0] = u0.x; uxp_a[1] = u0.y; uxp_a[2] = u0.z; uxp_a[3] = u0.w;
            uxp_b[0] = u1.x; uxp_b[1] = u1.y; uxp_b[2] = u1.z; uxp_b[3] = u1.w;
            const float* uxnp = UXN + ((size_t)(b0 + wid) * T_ + t) * 3;
            uxn_a = uxnp[0]; uxn_b = uxnp[1];
        } else if (wid < 4) {
            int row = wid - 2;
            const float* uxr = UX + ((size_t)(b0 + row) * T_ + t) * IN_;
            float4 u2 = *(const float4*)&uxr[512 + 4 * lane];
            uxp_a[0] = u2.x; uxp_a[1] = u2.y; uxp_a[2] = u2.z; uxp_a[3] = u2.w;
            uxn_a = UXN[((size_t)(b0 + row) * T_ + t) * 3 + 2];
        }

        {
            float a0 = 0.f, a1 = 0.f;
#pragma unroll
            for (int q = 0; q < 32; ++q) {
                uint4 hv0 = *(const uint4*)&h16u[0][q * 4];
                uint4 hv1 = *(const uint4*)&h16u[1][q * 4];
                a0 = dot2_(wA[q * 4 + 0], hv0.x, a0);
                a0 = dot2_(wA[q * 4 + 1], hv0.y, a0);
                a0 = dot2_(wA[q * 4 + 2], hv0.z, a0);
                a0 = dot2_(wA[q * 4 + 3], hv0.w, a0);
                a1 = dot2_(wA[q * 4 + 0], hv1.x, a1);
                a1 = dot2_(wA[q * 4 + 1], hv1.y, a1);
                a1 = dot2_(wA[q * 4 + 2], hv1.z, a1);
                a1 = dot2_(wA[q * 4 + 3], hv1.w, a1);
            }
            P1[0][tid] = a0;
            P1[1][tid] = a1;
        }
        __syncthreads();

        if (wid < 2) {
            int row = wid;
            float rr[4], tmp[4];
            float4 pr = *(const float4*)&P1[row][4 * lane];
            rr[0] = pr.x; rr[1] = pr.y; rr[2] = pr.z; rr[3] = pr.w;
            float rn = mvf_n(rr, hn_c);
            float n1 = madd_n(rr, uxp_a, rn * rn, uxn_a * uxn_a);
            {
                float4 br = *(const float4*)&bias_s[0][4 * lane];
                tmp[0] = br.x; tmp[1] = br.y; tmp[2] = br.z; tmp[3] = br.w;
            }
            float n2 = madd_n(rr, tmp, n1 * n1, bn0 * bn0);
            lsig_n(rr, n2);
            float rh[4];
            rhn_c = pmul_n(rr, hreg, rh, hn_c);
            c16u[row][2 * lane]     = packf16(rh[0], rh[1]);
            c16u[row][2 * lane + 1] = packf16(rh[2], rh[3]);
        } else if (wid < 4) {
            int row = wid - 2;
            float zr[4], tmp[4];
            float4 pz = *(const float4*)&P1[row][256 + 4 * lane];
            zr[0] = pz.x; zr[1] = pz.y; zr[2] = pz.z; zr[3] = pz.w;
            float hn_l = hns[row];
            float zn = mvf_n(zr, hn_l);
            float n1 = madd_n(zr, uxp_a, zn * zn, uxn_a * uxn_a);
            {
                float4 bz = *(const float4*)&bias_s[2][4 * lane];
                tmp[0] = bz.x; tmp[1] = bz.y; tmp[2] = bz.z; tmp[3] = bz.w;
            }
            float n2 = madd_n(zr, tmp, n1 * n1, bn2 * bn2);
            lsig_n(zr, n2);
            *(float4*)&zbuf[row][4 * lane] = make_float4(zr[0], zr[1], zr[2], zr[3]);
        }
        __syncthreads();

        {
            float c0 = 0.f, c1 = 0.f;
#pragma unroll
            for (int q = 0; q < 16; ++q) {
                uint4 cv0 = *(const uint4*)&c16u[0][kb2 + q * 4];
                uint4 cv1 = *(const uint4*)&c16u[1][kb2 + q * 4];
                c0 = dot2_(wB[q * 4 + 0], cv0.x, c0);
                c0 = dot2_(wB[q * 4 + 1], cv0.y, c0);
                c0 = dot2_(wB[q * 4 + 2], cv0.z, c0);
                c0 = dot2_(wB[q * 4 + 3], cv0.w, c0);
                c1 = dot2_(wB[q * 4 + 0], cv1.x, c1);
                c1 = dot2_(wB[q * 4 + 1], cv1.y, c1);
                c1 = dot2_(wB[q * 4 + 2], cv1.z, c1);
                c1 = dot2_(wB[q * 4 + 3], cv1.w, c1);
            }
            P2[half][0][j2i] = c0;
            P2[half][1][j2i] = c1;
        }
        __syncthreads();

        if (wid < 2) {
            int row = wid;
            float ht[4], tmp[4];
            float4 p0 = *(const float4*)&P2[0][row][4 * lane];
            float4 p1 = *(const float4*)&P2[1][row][4 * lane];
            ht[0] = p0.x + p1.x; ht[1] = p0.y + p1.y;
            ht[2] = p0.z + p1.z; ht[3] = p0.w + p1.w;
            float htn = mvf_n(ht, rhn_c);
            float n1 = madd_n(ht, uxp_b, htn * htn, uxn_b * uxn_b);
            {
                float4 bh = *(const float4*)&bias_s[1][4 * lane];
                tmp[0] = bh.x; tmp[1] = bh.y; tmp[2] = bh.z; tmp[3] = bh.w;
            }
            float n2 = madd_n(ht, tmp, n1 * n1, bn1 * bn1);
            float dl[4];
#pragma unroll
            for (int q = 0; q < 4; ++q) dl[q] = -hreg[q];
            float dn = madd_n(dl, ht, hn_c * hn_c, n2 * n2);
            float zv[4];
            {
                float4 zl = *(const float4*)&zbuf[row][4 * lane];
                zv[0] = zl.x; zv[1] = zl.y; zv[2] = zl.z; zv[3] = zl.w;
            }
            float dv[4];
            float dvn = pmul_n(zv, dl, dv, dn);
            float hn_new = madd_n(hreg, dv, hn_c * hn_c, dvn * dvn);
            hn_c = hn_new;
            float ncl = fmaxf(hn_new, EPS_);
            float ls = artanh_f(ncl) * frcp_(ncl);
            float* orow = Hfull + ((size_t)(b0 + row) * T_ + t) * H_;
            *(float4*)&orow[4 * lane] = make_float4(hreg[0] * ls, hreg[1] * ls, hreg[2] * ls, hreg[3] * ls);
            h16u[row][2 * lane]     = packf16(hreg[0], hreg[1]);
            h16u[row][2 * lane + 1] = packf16(hreg[2], hreg[3]);
            if (lane == 0) hns[row] = hn_new;
        }
        __syncthreads();
    }
}

// score[b,t] = v . tanh(S1 + b1 + q[b]) + bv, masked
__global__ __launch_bounds__(256) void k_score(
    const float* __restrict__ S1, const float* __restrict__ q,
    const float* __restrict__ b1, const float* __restrict__ av,
    const float* __restrict__ abv, const int* __restrict__ len,
    float* __restrict__ sc)
{
    int wid = threadIdx.x >> 6, lane = threadIdx.x & 63;
    int row = blockIdx.x * 4 + wid;
    int b = row / T_, t = row - b * T_;
    const float* s1 = S1 + (size_t)row * H_;
    const float* qp = q + (size_t)b * H_;
    float part = 0.f;
#pragma unroll
    for (int qq = 0; qq < 4; ++qq) {
        int j = lane + 64 * qq;
        float u = tanhf(s1[j] + b1[j] + qp[j]);
        part = fmaf(u, av[j], part);
    }
    part = wred(part) + abv[0];
    if (t >= len[b]) part = -1e9f;
    if (lane == 0) sc[row] = part;
}

// per-b: softmax over T, ctx = sum w*full, span logits + softmax -> d_out
__global__ __launch_bounds__(256) void k_ctx(
    const float* __restrict__ sc, const float* __restrict__ full,
    const float* __restrict__ spw, const float* __restrict__ spb,
    float* __restrict__ ctx, float* __restrict__ outsp)
{
    int b = blockIdx.x, tid = threadIdx.x;
    __shared__ float w_s[T_];
    __shared__ float cs[H_];
    __shared__ float red[NSPAN];
    if (tid < T_) w_s[tid] = sc[b * T_ + tid];
    __syncthreads();
    if (tid == 0) {
        float mx = -1e30f;
        for (int t = 0; t < T_; ++t) mx = fmaxf(mx, w_s[t]);
        float sum = 0.f;
        for (int t = 0; t < T_; ++t) { float e = expf(w_s[t] - mx); w_s[t] = e; sum += e; }
        float inv = 1.f / sum;
        for (int t = 0; t < T_; ++t) w_s[t] *= inv;
    }
    __syncthreads();
    float c = 0.f;
    for (int t = 0; t < T_; ++t) c = fmaf(w_s[t], full[((size_t)b * T_ + t) * H_ + tid], c);
    ctx[(size_t)b * H_ + tid] = c;
    cs[tid] = c;
    __syncthreads();
    if (tid < NSPAN) {
        float lg = spb[tid];
        for (int j = 0; j < H_; ++j) lg = fmaf(spw[tid * H_ + j], cs[j], lg);
        red[tid] = lg;
    }
    __syncthreads();
    if (tid == 0) {
        float mx = red[0];
        for (int k2 = 1; k2 < NSPAN; ++k2) mx = fmaxf(mx, red[k2]);
        float sum = 0.f;
        for (int k2 = 0; k2 < NSPAN; ++k2) sum += expf(red[k2] - mx);
        float inv = 1.f / sum;
        for (int k2 = 0; k2 < NSPAN; ++k2) outsp[(size_t)b * NSPAN + k2] = expf(red[k2] - mx) * inv;
    }
}

// ---------------- decoder v2 (R18 exact): LDS-staged weights, gate-aligned wave columns ----------------
#define WBS 40   // padded chunk row stride in ushorts (32 used + 8 pad; 80B, 16B-aligned)
__device__ __forceinline__ void dec_gemm(
    const unsigned short* __restrict__ W, int K, int NCH,
    const unsigned short* As, int ast,
    unsigned short* Wb0, unsigned short* Wb1,
    f32x4 acc[6], const int nb[6],
    int tid, int r16, int kq)
{
    uint4 regs[6];
#pragma unroll
    for (int r = 0; r < 6; ++r) {
        int task = tid + r * 512, n = task >> 2, sub = task & 3;
        regs[r] = *(const uint4*)&W[(size_t)n * K + sub * 8];
    }
#pragma unroll
    for (int r = 0; r < 6; ++r) {
        int task = tid + r * 512, n = task >> 2, sub = task & 3;
        *(uint4*)&Wb0[n * WBS + sub * 8] = regs[r];
    }
    __syncthreads();
    for (int c = 0; c < NCH; ++c) {
        unsigned short* cur = (c & 1) ? Wb1 : Wb0;
        unsigned short* nxt = (c & 1) ? Wb0 : Wb1;
        if (c + 1 < NCH) {
#pragma unroll
            for (int r = 0; r < 6; ++r) {
                int task = tid + r * 512, n = task >> 2, sub = task & 3;
                regs[r] = *(const uint4*)&W[(size_t)n * K + (c + 1) * 32 + sub * 8];
            }
        }
        bf16x8 a = *(const bf16x8*)&As[r16 * ast + c * 32 + kq * 8];
#pragma unroll
        for (int f = 0; f < 6; ++f) {
            bf16x8 b = *(const bf16x8*)&cur[(nb[f] + r16) * WBS + kq * 8];
            acc[f] = __builtin_amdgcn_mfma_f32_16x16x32_bf16(a, b, acc[f], 0, 0, 0);
        }
        if (c + 1 < NCH) {
#pragma unroll
            for (int r = 0; r < 6; ++r) {
                int task = tid + r * 512, n = task >> 2, sub = task & 3;
                *(uint4*)&nxt[n * WBS + sub * 8] = regs[r];
            }
        }
        __syncthreads();
    }
}

__global__ __launch_bounds__(512) void k_decoder(
    const float* __restrict__ ctx,
    const unsigned short* __restrict__ Wih,   // (768,768) bf16
    const unsigned short* __restrict__ Whh,   // (768,256) bf16
    const unsigned short* __restrict__ Wfc,   // (768,256) bf16
    const float* __restrict__ b_ih, const float* __restrict__ b_hh,
    const float* __restrict__ b_fc,
    const float* __restrict__ fow, const float* __restrict__ fob,
    float* __restrict__ outp)
{
    __shared__ __align__(16) unsigned short Wb[2][768 * WBS];  // 120 KB
    __shared__ __align__(16) unsigned short inp16[16][776];    // 24.25 KB
    __shared__ __align__(16) unsigned short h16d[16][264];     // 8.25 KB
    __shared__ float red_s[8][16][2];                          // 1 KB

    int tid = threadIdx.x;
    int wv = tid >> 6, l = tid & 63;
    int r0 = blockIdx.x * 16;
    int r16 = l & 15, kq = l >> 4;

    int nbg[6], nbf[6];
    float bih[6], bhh[6], bfc6[6];
#pragma unroll
    for (int f = 0; f < 6; ++f) {
        int g = f >> 1, d = f & 1;
        nbg[f] = g * 256 + wv * 32 + d * 16;
        bih[f] = b_ih[nbg[f] + r16];
        bhh[f] = b_hh[nbg[f] + r16];
        nbf[f] = wv * 96 + f * 16;
        bfc6[f] = b_fc[nbf[f] + r16];
    }
    float fowr[2][2];
#pragma unroll
    for (int o = 0; o < 2; ++o)
#pragma unroll
        for (int d = 0; d < 2; ++d) fowr[o][d] = fow[o * 256 + wv * 32 + d * 16 + r16];
    float fb0 = fob[0], fb1 = fob[1];

    for (int i = tid; i < 16 * 776; i += 512) ((unsigned short*)inp16)[i] = 0;
    for (int i = tid; i < 16 * 256; i += 512) {
        int row = i >> 8, c = i & 255;
        h16d[row][c] = f2bf_(ctx[(size_t)(r0 + row) * H_ + c]);
    }
    float hreg[2][4];
#pragma unroll
    for (int d = 0; d < 2; ++d)
#pragma unroll
        for (int q = 0; q < 4; ++q)
            hreg[d][q] = ctx[(size_t)(r0 + kq * 4 + q) * H_ + wv * 32 + d * 16 + r16];
    __syncthreads();

    for (int t = 0; t < NDAYS; ++t) {
        // ---- gi / gh GEMMs ----
        f32x4 gacc[6], hacc[6];
#pragma unroll
        for (int f = 0; f < 6; ++f) { gacc[f] = (f32x4){0.f,0.f,0.f,0.f}; hacc[f] = (f32x4){0.f,0.f,0.f,0.f}; }
        // t=0: inp == 0 -> gi is bias-only; skip the 24-chunk gi GEMM entirely.
        if (t > 0)
            dec_gemm(Wih, 768, 24, &inp16[0][0], 776, Wb[0], Wb[1], gacc, nbg, tid, r16, kq);
        dec_gemm(Whh, 256,  8, &h16d[0][0], 264, Wb[0], Wb[1], hacc, nbg, tid, r16, kq);
        // ---- GRU cell (lane-local) ----
#pragma unroll
        for (int d = 0; d < 2; ++d)
#pragma unroll
            for (int q = 0; q < 4; ++q) {
                float rr = frcp_(1.f + __expf(-(gacc[d][q] + bih[d] + hacc[d][q] + bhh[d])));
                float zz = frcp_(1.f + __expf(-(gacc[2 + d][q] + bih[2 + d] + hacc[2 + d][q] + bhh[2 + d])));
                float nn = tanhf(fmaf(rr, hacc[4 + d][q] + bhh[4 + d], gacc[4 + d][q] + bih[4 + d]));
                float hnew = (1.f - zz) * nn + zz * hreg[d][q];
                hreg[d][q] = hnew;
                h16d[kq * 4 + q][wv * 32 + d * 16 + r16] = f2bf_(hnew);
            }
        __syncthreads();
        // ---- inp' = relu(h @ Wfc^T + b_fc) ----
        if (t + 1 < NDAYS) {
            f32x4 iacc[6];
#pragma unroll
            for (int f = 0; f < 6; ++f) iacc[f] = (f32x4){0.f,0.f,0.f,0.f};
            dec_gemm(Wfc, 256, 8, &h16d[0][0], 264, Wb[0], Wb[1], iacc, nbf, tid, r16, kq);
#pragma unroll
            for (int f = 0; f < 6; ++f)
#pragma unroll
                for (int q = 0; q < 4; ++q)
                    inp16[kq * 4 + q][nbf[f] + r16] = f2bf_(fmaxf(iacc[f][q] + bfc6[f], 0.f));
        }
        // ---- fc_out: per-wave partials over its 32 cols, LDS reduce ----
        {
            float pq[2][4];
#pragma unroll
            for (int o = 0; o < 2; ++o)
#pragma unroll
                for (int q = 0; q < 4; ++q)
                    pq[o][q] = fmaf(hreg[0][q], fowr[o][0], hreg[1][q] * fowr[o][1]);
#pragma unroll
            for (int o = 0; o < 2; ++o)
#pragma unroll
                for (int q = 0; q < 4; ++q) {
                    float v = pq[o][q];
                    v += __shfl_xor(v, 1, 64); v += __shfl_xor(v, 2, 64);
                    v += __shfl_xor(v, 4, 64); v += __shfl_xor(v, 8, 64);
                    pq[o][q] = v;
                }
            if (r16 == 0) {
#pragma unroll
                for (int q = 0; q < 4; ++q) {
                    red_s[wv][kq * 4 + q][0] = pq[0][q];
                    red_s[wv][kq * 4 + q][1] = pq[1][q];
                }
            }
        }
        __syncthreads();
        if (tid < 16) {
            float l0 = fb0, l1 = fb1;
#pragma unroll
            for (int w = 0; w < 8; ++w) { l0 += red_s[w][tid][0]; l1 += red_s[w][tid][1]; }
            float mx = fmaxf(l0, l1);
            float e0 = __expf(l0 - mx), e1 = __expf(l1 - mx);
            float inv = frcp_(e0 + e1);
            float* op = outp + (size_t)(r0 + tid) * (NDAYS * OUTD) + t * OUTD;
            op[0] = e0 * inv; op[1] = e1 * inv;
        }
        __syncthreads();
    }
}

extern "C" void kernel_launch(void* const* d_in, const int* in_sizes, int n_in,
                              void* d_out, int out_size, void* d_ws, size_t ws_size,
                              hipStream_t stream)
{
    (void)in_sizes; (void)n_in; (void)out_size; (void)ws_size;
    const float* x        = (const float*)d_in[0];
    const int*   len      = (const int*)  d_in[1];
    const float* enc_w_ih = (const float*)d_in[2];
    const float* enc_w_hh = (const float*)d_in[3];
    const float* enc_bias = (const float*)d_in[4];
    const float* dec_w_ih = (const float*)d_in[5];
    const float* dec_w_hh = (const float*)d_in[6];
    const float* dec_b_ih = (const float*)d_in[7];
    const float* dec_b_hh = (const float*)d_in[8];
    const float* attn_w1  = (const float*)d_in[9];
    const float* attn_b1  = (const float*)d_in[10];
    const float* attn_w2  = (const float*)d_in[11];
    const float* attn_b2  = (const float*)d_in[12];
    const float* attn_v   = (const float*)d_in[13];
    const float* attn_bv  = (const float*)d_in[14];
    const float* fc_in_w  = (const float*)d_in[15];
    const float* fc_in_b  = (const float*)d_in[16];
    const float* fc_out_w = (const float*)d_in[17];
    const float* fc_out_b = (const float*)d_in[18];
    const float* span_w   = (const float*)d_in[19];
    const float* span_b   = (const float*)d_in[20];
    float* out = (float*)d_out;
    float* wsf = (float*)d_ws;

    const size_t ROWS = (size_t)B_ * T_;            // 38400
    float* UX    = wsf;                             // 38400*768
    float* Hfull = UX + ROWS * IN_;                 // 38400*256
    float* xs    = Hfull + ROWS * H_;               // 38400
    float* xnb   = xs + ROWS;                       // 38400
    float* WT    = xnb + ROWS;                      // 256*768 floats (packed enc weights)
    float* bvv   = WT + 256 * 768;                  // 768
    float* bvn   = bvv + 768;                       // 16 (3 used)
    float* UXN   = bvn + 16;                        // 38400*3
    float* qbuf  = UXN + ROWS * 3;                  // 512*256
    float* scb   = qbuf + (size_t)B_ * H_;          // 38400
    float* ctx   = scb + ROWS;                      // 512*256
    float* wpool = ctx + (size_t)B_ * H_;           // bf16 weight pool
    unsigned int* WPK = (unsigned int*)WT;
    unsigned short* Wencbf = (unsigned short*)wpool;                 // 768*768
    unsigned short* W1bf   = Wencbf + (size_t)768 * 768;             // 256*256
    unsigned short* W2bf   = W1bf + (size_t)256 * 256;               // 256*256
    unsigned short* DWIHbf = W2bf + (size_t)256 * 256;               // 768*768
    unsigned short* DWHHbf = DWIHbf + (size_t)768 * 768;             // 768*256
    unsigned short* FCINbf = DWHHbf + (size_t)768 * 256;             // 768*256
    float* S1 = UX;   // reuse after encoder consumes UX

    k_bias<<<1, 256, 0, stream>>>(enc_bias, bvv, bvn);
    k_packw<<<128, 256, 0, stream>>>(enc_w_hh, WPK);
    k_cvt_bf16<<<576, 256, 0, stream>>>(enc_w_ih, Wencbf, 768 * 768 / 4);
    k_cvt_bf16<<<64, 256, 0, stream>>>(attn_w1, W1bf, 256 * 256 / 4);
    k_cvt_bf16<<<64, 256, 0, stream>>>(attn_w2, W2bf, 256 * 256 / 4);
    k_cvt_bf16<<<576, 256, 0, stream>>>(dec_w_ih, DWIHbf, 768 * 768 / 4);
    k_cvt_bf16<<<192, 256, 0, stream>>>(dec_w_hh, DWHHbf, 768 * 256 / 4);
    k_cvt_bf16<<<192, 256, 0, stream>>>(fc_in_w, FCINbf, 768 * 256 / 4);
    k_row_scale<<<(unsigned)(ROWS / 4), 256, 0, stream>>>(x, xs, xnb);
    k_gemm_mfma<<<dim3(IN_ / 192, (unsigned)(ROWS / 128)), 256, 0, stream>>>(x, Wencbf, UX, (int)ROWS, IN_, IN_);
    k_ux_scale<<<(unsigned)(ROWS * 3 / 4), 256, 0, stream>>>(UX, xs, xnb, UXN);
    k_encoder<<<B_ / 2, 512, 0, stream>>>(UX, WPK, bvv, bvn, UXN, Hfull);
    // Hfull is already logmapped. q = hx @ w2^T + b2 (hx = rows t=T-1, stride T*H)
    k_gemm_mfma_g<<<dim3(H_ / 128, B_ / 128), 256, 0, stream>>>(Hfull + (T_ - 1) * H_, T_ * H_, W2bf, attn_b2, qbuf, H_, H_, 0);
    k_gemm_mfma_g<<<dim3(H_ / 128, (unsigned)(ROWS / 128)), 256, 0, stream>>>(Hfull, H_, W1bf, nullptr, S1, H_, H_, 0);
    k_score<<<(unsigned)(ROWS / 4), 256, 0, stream>>>(S1, qbuf, attn_b1, attn_v, attn_bv, len, scb);
    k_ctx<<<B_, 256, 0, stream>>>(scb, Hfull, span_w, span_b, ctx, out);
    k_decoder<<<B_ / 16, 512, 0, stream>>>(ctx, DWIHbf, DWHHbf, FCINbf,
                                           dec_b_ih, dec_b_hh, fc_in_b,
                                           fc_out_w, fc_out_b, out + B_ * NSPAN);
}

// Round 21
// 1308.195 us; speedup vs baseline: 1.1068x; 1.0399x over previous
//
#include <hip/hip_runtime.h>
#include <hip/hip_fp16.h>
#include <math.h>

#define B_    512
#define T_    75
#define IN_   768
#define H_    256
#define NSPAN 8
#define OUTD  2
#define NDAYS 10
#define EPS_  1e-5f
#define MAXN_ 0.999f
#define CLIP_ (1.0f - 1e-7f)

typedef short bf16x8 __attribute__((ext_vector_type(8)));
typedef float f32x4 __attribute__((ext_vector_type(4)));

// ---------------- wave helpers (wave = 64 lanes) ----------------
// DPP-based wave reduction: VALU pipe instead of ds_swizzle.
template<int CTRL, int RMASK>
__device__ __forceinline__ float dppadd_(float v) {
    return v + __int_as_float(__builtin_amdgcn_update_dpp(
        0, __float_as_int(v), CTRL, RMASK, 0xf, true));
}
__device__ __forceinline__ float wred(float v) {
    v = dppadd_<0x111, 0xf>(v);   // row_shr:1
    v = dppadd_<0x112, 0xf>(v);   // row_shr:2
    v = dppadd_<0x114, 0xf>(v);   // row_shr:4
    v = dppadd_<0x118, 0xf>(v);   // row_shr:8
    v = dppadd_<0x142, 0xa>(v);   // row_bcast:15
    v = dppadd_<0x143, 0xc>(v);   // row_bcast:31; lane63 = total
    return __int_as_float(__builtin_amdgcn_readlane(__float_as_int(v), 63));
}
__device__ __forceinline__ float artanh_(float x) {
    x = fminf(x, CLIP_);
    return 0.5f * logf((1.f + x) / (1.f - x));
}
__device__ __forceinline__ float sigm_(float x) { return 1.f / (1.f + expf(-x)); }
__device__ __forceinline__ float h2f_(unsigned short u) {
    union { unsigned short us; __half h; } cv; cv.us = u;
    return __half2float(cv.h);
}
__device__ __forceinline__ unsigned int packf16(float a, float b) {
    union { __half h; unsigned short us; } ca, cb;
    ca.h = __float2half(a); cb.h = __float2half(b);
    return (unsigned int)ca.us | ((unsigned int)cb.us << 16);
}
__device__ __forceinline__ unsigned short f2bf_(float f) {  // RNE f32->bf16
    union { float f; unsigned u; } c; c.f = f;
    unsigned r = c.u + 0x7fff + ((c.u >> 16) & 1);
    return (unsigned short)(r >> 16);
}
// f16-pair dot product with f32 accumulator
__device__ __forceinline__ float dot2_(unsigned int w, unsigned int h, float acc) {
#if __has_builtin(__builtin_amdgcn_fdot2)
    typedef _Float16 h2_t __attribute__((ext_vector_type(2)));
    union { unsigned int u; h2_t v; } a, b;
    a.u = w; b.u = h;
    return __builtin_amdgcn_fdot2(a.v, b.v, acc, false);
#else
    float wx = h2f_((unsigned short)(w & 0xffff)), wy = h2f_((unsigned short)(w >> 16));
    float hx = h2f_((unsigned short)(h & 0xffff)), hy = h2f_((unsigned short)(h >> 16));
    return fmaf(wy, hy, fmaf(wx, hx, acc));
#endif
}
// ---- fast-math (encoder hot path). Args are wave-uniform norms >= 0. ----
__device__ __forceinline__ float frcp_(float x) { return __builtin_amdgcn_rcpf(x); }
__device__ __forceinline__ float tanh_f(float x) {
    if (x < 0.01f) return x * (1.f - 0.33333334f * x * x);
    return 1.f - 2.f * frcp_(__expf(2.f * x) + 1.f);
}
__device__ __forceinline__ float artanh_f(float x) {
    x = fminf(x, CLIP_);
    if (x < 0.01f) return x * (1.f + 0.33333334f * x * x);
    return 0.5f * __logf((1.f + x) * frcp_(1.f - x));
}

// -------- norm-carrying mobius primitives (wave owns 256-vec, 4/lane) --------
__device__ __forceinline__ float wsum4(const float* v) {
    float ss = 0.f;
#pragma unroll
    for (int q = 0; q < 4; ++q) ss = fmaf(v[q], v[q], ss);
    return wred(ss);
}
__device__ __forceinline__ float mvf_n(float* v, float xn_raw) {
    float n = fmaxf(sqrtf(fmaxf(wsum4(v), 1e-15f)), EPS_);
    float xc = fmaxf(xn_raw, EPS_);
    float tt = tanh_f(n * frcp_(xc) * artanh_f(xc));
    float sc = tt * frcp_(n);
    float outn = tt;
    if (tt > MAXN_) { sc = MAXN_ * frcp_(n); outn = MAXN_; }
#pragma unroll
    for (int q = 0; q < 4; ++q) v[q] *= sc;
    return outn;
}
__device__ __forceinline__ float madd_n(float* x, const float* y, float x2, float y2) {
    float xy = 0.f;
#pragma unroll
    for (int q = 0; q < 4; ++q) xy = fmaf(x[q], y[q], xy);
    xy = wred(xy);
    float den = fmaxf(1.f + 2.f * xy + x2 * y2, EPS_);
    float cx = 1.f + 2.f * xy + y2, cy = 1.f - x2;
#pragma unroll
    for (int q = 0; q < 4; ++q) x[q] = cx * x[q] + cy * y[q];
    float nn = fmaf(cx * cx, x2, fmaf(2.f * cx * cy, xy, cy * cy * y2));
    float inv = frcp_(den);
    float pn = sqrtf(fmaxf(nn, 1e-15f)) * inv;
    float s = inv, outn = pn;
    if (pn > MAXN_) { s *= MAXN_ * frcp_(pn); outn = MAXN_; }
#pragma unroll
    for (int q = 0; q < 4; ++q) x[q] *= s;
    return outn;
}
__device__ __forceinline__ void lsig_n(float* v, float n_raw) {
    float nc = fmaxf(n_raw, EPS_);
    float s = artanh_f(nc) * frcp_(nc);
#pragma unroll
    for (int q = 0; q < 4; ++q) v[q] = frcp_(1.f + __expf(-v[q] * s));
}
__device__ __forceinline__ float pmul_n(const float* w, const float* x, float* o, float xn_raw) {
    float xc = fmaxf(xn_raw, EPS_);
#pragma unroll
    for (int q = 0; q < 4; ++q) o[q] = w[q] * x[q];
    float wxn = fmaxf(sqrtf(fmaxf(wsum4(o), 1e-15f)), EPS_);
    float tt = tanh_f(wxn * frcp_(xc) * artanh_f(xc));
    float sc = tt * frcp_(wxn);
    float outn = tt;
    if (tt > MAXN_) { sc = MAXN_ * frcp_(wxn); outn = MAXN_; }
#pragma unroll
    for (int q = 0; q < 4; ++q) o[q] *= sc;
    return outn;
}

// ---------------- prep kernels ----------------
__global__ __launch_bounds__(256) void k_bias(const float* __restrict__ eb, float* __restrict__ bv,
                                              float* __restrict__ bvn) {
    int wid = threadIdx.x >> 6, lane = threadIdx.x & 63;
    if (wid >= 3) return;
    const float* p = eb + wid * H_;
    float v0 = p[lane], v1 = p[lane + 64], v2 = p[lane + 128], v3 = p[lane + 192];
    float ss = wred(v0 * v0 + v1 * v1 + v2 * v2 + v3 * v3);
    float n = sqrtf(fmaxf(ss, 1e-15f));
    float nc = fmaxf(n, EPS_);
    float s = tanhf(nc) / nc;
    float nv = n * s;
    float fn = nv;
    if (nv > MAXN_) { s *= MAXN_ / nv; fn = MAXN_; }
    bv[wid * H_ + lane] = v0 * s;
    bv[wid * H_ + lane + 64] = v1 * s;
    bv[wid * H_ + lane + 128] = v2 * s;
    bv[wid * H_ + lane + 192] = v3 * s;
    if (lane == 0) bvn[wid] = fn;
}

__global__ __launch_bounds__(256) void k_packw(const float* __restrict__ whh, unsigned int* __restrict__ WPK) {
    int kp = blockIdx.x;
    for (int j = threadIdx.x; j < 768; j += 256) {
        float w0 = whh[(size_t)j * 256 + 2 * kp];
        float w1 = whh[(size_t)j * 256 + 2 * kp + 1];
        WPK[(size_t)kp * 768 + j] = packf16(w0, w1);
    }
}

// merged f32 -> bf16 conversion over 6 weight regions (saves 5 launches)
#define CV0 147456   // enc_w_ih  768*768/4
#define CV1 163840   // + attn_w1 256*256/4
#define CV2 180224   // + attn_w2
#define CV3 327680   // + dec_w_ih 768*768/4
#define CV4 376832   // + dec_w_hh 768*256/4
#define CV5 425984   // + fc_in_w  768*256/4
__global__ __launch_bounds__(256) void k_cvt_all(
    const float* __restrict__ s0, const float* __restrict__ s1, const float* __restrict__ s2,
    const float* __restrict__ s3, const float* __restrict__ s4, const float* __restrict__ s5,
    unsigned short* __restrict__ d0, unsigned short* __restrict__ d1, unsigned short* __restrict__ d2,
    unsigned short* __restrict__ d3, unsigned short* __restrict__ d4, unsigned short* __restrict__ d5)
{
    int i = blockIdx.x * 256 + threadIdx.x;
    if (i >= CV5) return;
    const float* src; unsigned short* dst; int off;
    if      (i < CV0) { src = s0; dst = d0; off = i; }
    else if (i < CV1) { src = s1; dst = d1; off = i - CV0; }
    else if (i < CV2) { src = s2; dst = d2; off = i - CV1; }
    else if (i < CV3) { src = s3; dst = d3; off = i - CV2; }
    else if (i < CV4) { src = s4; dst = d4; off = i - CV3; }
    else              { src = s5; dst = d5; off = i - CV4; }
    float4 v = *(const float4*)&src[(size_t)off * 4];
    ushort4 o;
    o.x = f2bf_(v.x); o.y = f2bf_(v.y); o.z = f2bf_(v.z); o.w = f2bf_(v.w);
    *(ushort4*)&dst[(size_t)off * 4] = o;
}

__global__ __launch_bounds__(256) void k_row_scale(const float* __restrict__ x, float* __restrict__ xs, float* __restrict__ xn) {
    int wid = threadIdx.x >> 6, lane = threadIdx.x & 63;
    int row = blockIdx.x * 4 + wid;
    const float* p = x + (size_t)row * IN_;
    float ss = 0.f;
#pragma unroll
    for (int q = 0; q < 12; ++q) { float v = p[lane + 64 * q]; ss = fmaf(v, v, ss); }
    ss = wred(ss);
    float n = sqrtf(fmaxf(ss, 1e-15f));
    float nc = fmaxf(n, EPS_);
    float s = tanhf(nc) / nc;
    float nv = n * s;
    if (nv > MAXN_) s *= MAXN_ / nv;
    if (lane == 0) { xs[row] = s; xn[row] = fmaxf(n * s, EPS_); }
}

// combine per-gate norm partials -> per-(row,gate) scale UXS and final norm UXN
__global__ __launch_bounds__(256) void k_uxn(
    const float* __restrict__ UXP2, const float* __restrict__ xs, const float* __restrict__ xnb,
    float* __restrict__ UXS, float* __restrict__ UXN)
{
    int rg = blockIdx.x * 256 + threadIdx.x;
    if (rg >= 38400 * 3) return;
    int row = rg / 3, g = rg - row * 3;
    float ss = UXP2[(size_t)row * 6 + g * 2] + UXP2[(size_t)row * 6 + g * 2 + 1];
    float s = xs[row], xv = xnb[row];
    float ssc = s * s * ss;
    float mxn = fmaxf(sqrtf(fmaxf(ssc, 1e-15f)), EPS_);
    float tt = tanhf(mxn / xv * artanh_(xv));
    float sc = tt / mxn;
    float fn = tt;
    if (tt > MAXN_) { sc = MAXN_ / mxn; fn = MAXN_; }
    UXS[rg] = s * sc;
    UXN[rg] = fn;
}

// ---------------- MFMA bf16 GEMM (192-N tile) + per-gate norm partials (UX path) ----------------
// Writes raw C = x @ Wenc^T AND per-(row,gate) sum-of-squares partials into fixed slots:
// nt0 -> g0 slot0; nt1 -> g0 slot1 (nj<4), g1 slot0 (nj>=4); nt2 -> g1 slot1 (nj<8), g2 slot0; nt3 -> g2 slot1.
__global__ __launch_bounds__(256) void k_gemm_ux(
    const float* __restrict__ A, const unsigned short* __restrict__ Wbf,
    float* __restrict__ C, float* __restrict__ UXP2)
{
    int wv = threadIdx.x >> 6, l = threadIdx.x & 63;
    int m0 = blockIdx.y * 128 + wv * 32;
    int nt = blockIdx.x;
    int n0 = nt * 192;
    int r16 = l & 15, kq = l >> 4;
    f32x4 acc[2][12];
#pragma unroll
    for (int i = 0; i < 2; ++i)
#pragma unroll
        for (int j = 0; j < 12; ++j) acc[i][j] = (f32x4){0.f, 0.f, 0.f, 0.f};

    for (int k0 = 0; k0 < IN_; k0 += 32) {
        bf16x8 af[2];
#pragma unroll
        for (int mi = 0; mi < 2; ++mi) {
            const float* ap = A + (size_t)(m0 + mi * 16 + r16) * IN_ + k0 + kq * 8;
            float4 x0 = *(const float4*)ap;
            float4 x1 = *(const float4*)(ap + 4);
            af[mi][0] = (short)f2bf_(x0.x); af[mi][1] = (short)f2bf_(x0.y);
            af[mi][2] = (short)f2bf_(x0.z); af[mi][3] = (short)f2bf_(x0.w);
            af[mi][4] = (short)f2bf_(x1.x); af[mi][5] = (short)f2bf_(x1.y);
            af[mi][6] = (short)f2bf_(x1.z); af[mi][7] = (short)f2bf_(x1.w);
        }
#pragma unroll
        for (int nj = 0; nj < 12; ++nj) {
            bf16x8 bf = *(const bf16x8*)(Wbf + (size_t)(n0 + nj * 16 + r16) * IN_ + k0 + kq * 8);
            acc[0][nj] = __builtin_amdgcn_mfma_f32_16x16x32_bf16(af[0], bf, acc[0][nj], 0, 0, 0);
            acc[1][nj] = __builtin_amdgcn_mfma_f32_16x16x32_bf16(af[1], bf, acc[1][nj], 0, 0, 0);
        }
    }
    // raw C write
#pragma unroll
    for (int mi = 0; mi < 2; ++mi)
#pragma unroll
        for (int nj = 0; nj < 12; ++nj)
#pragma unroll
            for (int q = 0; q < 4; ++q)
                C[(size_t)(m0 + mi * 16 + kq * 4 + q) * IN_ + n0 + nj * 16 + r16] = acc[mi][nj][q];
    // per-gate norm partials
    int split, idxA, idxB;
    if      (nt == 0) { split = 12; idxA = 0;  idxB = -1; }
    else if (nt == 1) { split = 4;  idxA = 1;  idxB = 2;  }
    else if (nt == 2) { split = 8;  idxA = 3;  idxB = 4;  }
    else              { split = 0;  idxA = -1; idxB = 5;  }
#pragma unroll
    for (int mi = 0; mi < 2; ++mi)
#pragma unroll
        for (int q = 0; q < 4; ++q) {
            int row = m0 + mi * 16 + kq * 4 + q;
            float ssA = 0.f, ssB = 0.f;
#pragma unroll
            for (int nj = 0; nj < 12; ++nj) {
                float v = acc[mi][nj][q];
                if (nj < split) ssA = fmaf(v, v, ssA);
                else            ssB = fmaf(v, v, ssB);
            }
            ssA += __shfl_xor(ssA, 1, 64); ssA += __shfl_xor(ssA, 2, 64);
            ssA += __shfl_xor(ssA, 4, 64); ssA += __shfl_xor(ssA, 8, 64);
            ssB += __shfl_xor(ssB, 1, 64); ssB += __shfl_xor(ssB, 2, 64);
            ssB += __shfl_xor(ssB, 4, 64); ssB += __shfl_xor(ssB, 8, 64);
            if (r16 == 0) {
                if (idxA >= 0) UXP2[(size_t)row * 6 + idxA] = ssA;
                if (idxB >= 0) UXP2[(size_t)row * 6 + idxB] = ssB;
            }
        }
}

// ---------------- general MFMA bf16 GEMM (128-N tile): C = A @ Wbf^T (+bias)(+relu) ----------------
__global__ __launch_bounds__(256) void k_gemm_mfma_g(
    const float* __restrict__ A, int lda,
    const unsigned short* __restrict__ Wbf,
    const float* __restrict__ bias,
    float* __restrict__ C, int N, int K, int act)
{
    int wv = threadIdx.x >> 6, l = threadIdx.x & 63;
    int m0 = blockIdx.y * 128 + wv * 32;
    int n0 = blockIdx.x * 128;
    int r16 = l & 15, kq = l >> 4;
    f32x4 acc[2][8];
#pragma unroll
    for (int i = 0; i < 2; ++i)
#pragma unroll
        for (int j = 0; j < 8; ++j) acc[i][j] = (f32x4){0.f, 0.f, 0.f, 0.f};

    for (int k0 = 0; k0 < K; k0 += 32) {
        bf16x8 af[2];
#pragma unroll
        for (int mi = 0; mi < 2; ++mi) {
            const float* ap = A + (size_t)(m0 + mi * 16 + r16) * lda + k0 + kq * 8;
            float4 x0 = *(const float4*)ap;
            float4 x1 = *(const float4*)(ap + 4);
            af[mi][0] = (short)f2bf_(x0.x); af[mi][1] = (short)f2bf_(x0.y);
            af[mi][2] = (short)f2bf_(x0.z); af[mi][3] = (short)f2bf_(x0.w);
            af[mi][4] = (short)f2bf_(x1.x); af[mi][5] = (short)f2bf_(x1.y);
            af[mi][6] = (short)f2bf_(x1.z); af[mi][7] = (short)f2bf_(x1.w);
        }
#pragma unroll
        for (int nj = 0; nj < 8; ++nj) {
            bf16x8 bf = *(const bf16x8*)(Wbf + (size_t)(n0 + nj * 16 + r16) * K + k0 + kq * 8);
            acc[0][nj] = __builtin_amdgcn_mfma_f32_16x16x32_bf16(af[0], bf, acc[0][nj], 0, 0, 0);
            acc[1][nj] = __builtin_amdgcn_mfma_f32_16x16x32_bf16(af[1], bf, acc[1][nj], 0, 0, 0);
        }
    }
#pragma unroll
    for (int mi = 0; mi < 2; ++mi)
#pragma unroll
        for (int nj = 0; nj < 8; ++nj) {
            int col = n0 + nj * 16 + r16;
            float bb = bias ? bias[col] : 0.f;
#pragma unroll
            for (int q = 0; q < 4; ++q) {
                float v = acc[mi][nj][q] + bb;
                if (act) v = fmaxf(v, 0.f);
                C[(size_t)(m0 + mi * 16 + kq * 4 + q) * N + col] = v;
            }
        }
}

// ---------------- mobius GRU encoder v12: R11 structure + UXS scale-at-load ----------------
__global__ __launch_bounds__(512) void k_encoder(
    const float* __restrict__ UX, const unsigned int* __restrict__ WPK,
    const float* __restrict__ bv, const float* __restrict__ bvn,
    const float* __restrict__ UXN, const float* __restrict__ UXS,
    float* __restrict__ Hfull)
{
    __shared__ __align__(16) unsigned int h16u[2][128];
    __shared__ __align__(16) unsigned int c16u[2][128];
    __shared__ float P1[2][512];
    __shared__ float P2[2][2][256];
    __shared__ float bias_s[3][256];
    __shared__ float zbuf[2][256];
    __shared__ float hns[2];

    int tid = threadIdx.x;
    int wid = tid >> 6, lane = tid & 63;
    int b0 = blockIdx.x * 2;

    for (int i = tid; i < 768; i += 512) bias_s[i >> 8][i & 255] = bv[i];
    if (tid < 256) h16u[tid >> 7][tid & 127] = 0u;
    if (tid < 2) hns[tid] = 0.f;
    __syncthreads();

    float bn0 = bvn[0], bn1 = bvn[1], bn2 = bvn[2];

    int j1 = (tid < 256) ? tid : (tid + 256);
    unsigned int wA[128];
#pragma unroll
    for (int kp = 0; kp < 128; ++kp) wA[kp] = WPK[(size_t)kp * 768 + j1];
    int j2i = tid & 255;
    int half = tid >> 8;
    int kb2 = half * 64;
    unsigned int wB[64];
#pragma unroll
    for (int i = 0; i < 64; ++i) wB[i] = WPK[(size_t)(kb2 + i) * 768 + 256 + j2i];

    float hreg[4] = {0.f, 0.f, 0.f, 0.f};
    float hn_c = 0.f;
    float rhn_c = 0.f;

    for (int t = 0; t < T_; ++t) {
        float uxp_a[4], uxp_b[4];
        float uxn_a = 0.f, uxn_b = 0.f;
        if (wid < 2) {
            const float* uxr = UX + ((size_t)(b0 + wid) * T_ + t) * IN_;
            size_t rg3 = ((size_t)(b0 + wid) * T_ + t) * 3;
            float sa = UXS[rg3], sb = UXS[rg3 + 1];
            float4 u0 = *(const float4*)&uxr[4 * lane];
            float4 u1 = *(const float4*)&uxr[256 + 4 * lane];
            uxp_a[0] = u0.x * sa; uxp_a[1] = u0.y * sa; uxp_a[2] = u0.z * sa; uxp_a[3] = u0.w * sa;
            uxp_b[0] = u1.x * sb; uxp_b[1] = u1.y * sb; uxp_b[2] = u1.z * sb; uxp_b[3] = u1.w * sb;
            uxn_a = UXN[rg3]; uxn_b = UXN[rg3 + 1];
        } else if (wid < 4) {
            int row = wid - 2;
            const float* uxr = UX + ((size_t)(b0 + row) * T_ + t) * IN_;
            size_t rg3 = ((size_t)(b0 + row) * T_ + t) * 3;
            float sz = UXS[rg3 + 2];
            float4 u2 = *(const float4*)&uxr[512 + 4 * lane];
            uxp_a[0] = u2.x * sz; uxp_a[1] = u2.y * sz; uxp_a[2] = u2.z * sz; uxp_a[3] = u2.w * sz;
            uxn_a = UXN[rg3 + 2];
        }

        {
            float a0 = 0.f, a1 = 0.f;
#pragma unroll
            for (int q = 0; q < 32; ++q) {
                uint4 hv0 = *(const uint4*)&h16u[0][q * 4];
                uint4 hv1 = *(const uint4*)&h16u[1][q * 4];
                a0 = dot2_(wA[q * 4 + 0], hv0.x, a0);
                a0 = dot2_(wA[q * 4 + 1], hv0.y, a0);
                a0 = dot2_(wA[q * 4 + 2], hv0.z, a0);
                a0 = dot2_(wA[q * 4 + 3], hv0.w, a0);
                a1 = dot2_(wA[q * 4 + 0], hv1.x, a1);
                a1 = dot2_(wA[q * 4 + 1], hv1.y, a1);
                a1 = dot2_(wA[q * 4 + 2], hv1.z, a1);
                a1 = dot2_(wA[q * 4 + 3], hv1.w, a1);
            }
            P1[0][tid] = a0;
            P1[1][tid] = a1;
        }
        __syncthreads();

        if (wid < 2) {
            int row = wid;
            float rr[4], tmp[4];
            float4 pr = *(const float4*)&P1[row][4 * lane];
            rr[0] = pr.x; rr[1] = pr.y; rr[2] = pr.z; rr[3] = pr.w;
            float rn = mvf_n(rr, hn_c);
            float n1 = madd_n(rr, uxp_a, rn * rn, uxn_a * uxn_a);
            {
                float4 br = *(const float4*)&bias_s[0][4 * lane];
                tmp[0] = br.x; tmp[1] = br.y; tmp[2] = br.z; tmp[3] = br.w;
            }
            float n2 = madd_n(rr, tmp, n1 * n1, bn0 * bn0);
            lsig_n(rr, n2);
            float rh[4];
            rhn_c = pmul_n(rr, hreg, rh, hn_c);
            c16u[row][2 * lane]     = packf16(rh[0], rh[1]);
            c16u[row][2 * lane + 1] = packf16(rh[2], rh[3]);
        } else if (wid < 4) {
            int row = wid - 2;
            float zr[4], tmp[4];
            float4 pz = *(const float4*)&P1[row][256 + 4 * lane];
            zr[0] = pz.x; zr[1] = pz.y; zr[2] = pz.z; zr[3] = pz.w;
            float hn_l = hns[row];
            float zn = mvf_n(zr, hn_l);
            float n1 = madd_n(zr, uxp_a, zn * zn, uxn_a * uxn_a);
            {
                float4 bz = *(const float4*)&bias_s[2][4 * lane];
                tmp[0] = bz.x; tmp[1] = bz.y; tmp[2] = bz.z; tmp[3] = bz.w;
            }
            float n2 = madd_n(zr, tmp, n1 * n1, bn2 * bn2);
            lsig_n(zr, n2);
            *(float4*)&zbuf[row][4 * lane] = make_float4(zr[0], zr[1], zr[2], zr[3]);
        }
        __syncthreads();

        {
            float c0 = 0.f, c1 = 0.f;
#pragma unroll
            for (int q = 0; q < 16; ++q) {
                uint4 cv0 = *(const uint4*)&c16u[0][kb2 + q * 4];
                uint4 cv1 = *(const uint4*)&c16u[1][kb2 + q * 4];
                c0 = dot2_(wB[q * 4 + 0], cv0.x, c0);
                c0 = dot2_(wB[q * 4 + 1], cv0.y, c0);
                c0 = dot2_(wB[q * 4 + 2], cv0.z, c0);
                c0 = dot2_(wB[q * 4 + 3], cv0.w, c0);
                c1 = dot2_(wB[q * 4 + 0], cv1.x, c1);
                c1 = dot2_(wB[q * 4 + 1], cv1.y, c1);
                c1 = dot2_(wB[q * 4 + 2], cv1.z, c1);
                c1 = dot2_(wB[q * 4 + 3], cv1.w, c1);
            }
            P2[half][0][j2i] = c0;
            P2[half][1][j2i] = c1;
        }
        __syncthreads();

        if (wid < 2) {
            int row = wid;
            float ht[4], tmp[4];
            float4 p0 = *(const float4*)&P2[0][row][4 * lane];
            float4 p1 = *(const float4*)&P2[1][row][4 * lane];
            ht[0] = p0.x + p1.x; ht[1] = p0.y + p1.y;
            ht[2] = p0.z + p1.z; ht[3] = p0.w + p1.w;
            float htn = mvf_n(ht, rhn_c);
            float n1 = madd_n(ht, uxp_b, htn * htn, uxn_b * uxn_b);
            {
                float4 bh = *(const float4*)&bias_s[1][4 * lane];
                tmp[0] = bh.x; tmp[1] = bh.y; tmp[2] = bh.z; tmp[3] = bh.w;
            }
            float n2 = madd_n(ht, tmp, n1 * n1, bn1 * bn1);
            float dl[4];
#pragma unroll
            for (int q = 0; q < 4; ++q) dl[q] = -hreg[q];
            float dn = madd_n(dl, ht, hn_c * hn_c, n2 * n2);
            float zv[4];
            {
                float4 zl = *(const float4*)&zbuf[row][4 * lane];
                zv[0] = zl.x; zv[1] = zl.y; zv[2] = zl.z; zv[3] = zl.w;
            }
            float dv[4];
            float dvn = pmul_n(zv, dl, dv, dn);
            float hn_new = madd_n(hreg, dv, hn_c * hn_c, dvn * dvn);
            hn_c = hn_new;
            float ncl = fmaxf(hn_new, EPS_);
            float ls = artanh_f(ncl) * frcp_(ncl);
            float* orow = Hfull + ((size_t)(b0 + row) * T_ + t) * H_;
            *(float4*)&orow[4 * lane] = make_float4(hreg[0] * ls, hreg[1] * ls, hreg[2] * ls, hreg[3] * ls);
            h16u[row][2 * lane]     = packf16(hreg[0], hreg[1]);
            h16u[row][2 * lane + 1] = packf16(hreg[2], hreg[3]);
            if (lane == 0) hns[row] = hn_new;
        }
        __syncthreads();
    }
}

// score[b,t] = v . tanh(S1 + b1 + q[b]) + bv, masked
__global__ __launch_bounds__(256) void k_score(
    const float* __restrict__ S1, const float* __restrict__ q,
    const float* __restrict__ b1, const float* __restrict__ av,
    const float* __restrict__ abv, const int* __restrict__ len,
    float* __restrict__ sc)
{
    int wid = threadIdx.x >> 6, lane = threadIdx.x & 63;
    int row = blockIdx.x * 4 + wid;
    int b = row / T_, t = row - b * T_;
    const float* s1 = S1 + (size_t)row * H_;
    const float* qp = q + (size_t)b * H_;
    float part = 0.f;
#pragma unroll
    for (int qq = 0; qq < 4; ++qq) {
        int j = lane + 64 * qq;
        float u = tanhf(s1[j] + b1[j] + qp[j]);
        part = fmaf(u, av[j], part);
    }
    part = wred(part) + abv[0];
    if (t >= len[b]) part = -1e9f;
    if (lane == 0) sc[row] = part;
}

// per-b: softmax over T, ctx = sum w*full, span logits + softmax -> d_out
__global__ __launch_bounds__(256) void k_ctx(
    const float* __restrict__ sc, const float* __restrict__ full,
    const float* __restrict__ spw, const float* __restrict__ spb,
    float* __restrict__ ctx, float* __restrict__ outsp)
{
    int b = blockIdx.x, tid = threadIdx.x;
    __shared__ float w_s[T_];
    __shared__ float cs[H_];
    __shared__ float red[NSPAN];
    if (tid < T_) w_s[tid] = sc[b * T_ + tid];
    __syncthreads();
    if (tid == 0) {
        float mx = -1e30f;
        for (int t = 0; t < T_; ++t) mx = fmaxf(mx, w_s[t]);
        float sum = 0.f;
        for (int t = 0; t < T_; ++t) { float e = expf(w_s[t] - mx); w_s[t] = e; sum += e; }
        float inv = 1.f / sum;
        for (int t = 0; t < T_; ++t) w_s[t] *= inv;
    }
    __syncthreads();
    float c = 0.f;
    for (int t = 0; t < T_; ++t) c = fmaf(w_s[t], full[((size_t)b * T_ + t) * H_ + tid], c);
    ctx[(size_t)b * H_ + tid] = c;
    cs[tid] = c;
    __syncthreads();
    if (tid < NSPAN) {
        float lg = spb[tid];
        for (int j = 0; j < H_; ++j) lg = fmaf(spw[tid * H_ + j], cs[j], lg);
        red[tid] = lg;
    }
    __syncthreads();
    if (tid == 0) {
        float mx = red[0];
        for (int k2 = 1; k2 < NSPAN; ++k2) mx = fmaxf(mx, red[k2]);
        float sum = 0.f;
        for (int k2 = 0; k2 < NSPAN; ++k2) sum += expf(red[k2] - mx);
        float inv = 1.f / sum;
        for (int k2 = 0; k2 < NSPAN; ++k2) outsp[(size_t)b * NSPAN + k2] = expf(red[k2] - mx) * inv;
    }
}

// ---------------- decoder v2 (R18 exact): LDS-staged weights, gate-aligned wave columns ----------------
#define WBS 40   // padded chunk row stride in ushorts (32 used + 8 pad; 80B, 16B-aligned)
__device__ __forceinline__ void dec_gemm(
    const unsigned short* __restrict__ W, int K, int NCH,
    const unsigned short* As, int ast,
    unsigned short* Wb0, unsigned short* Wb1,
    f32x4 acc[6], const int nb[6],
    int tid, int r16, int kq)
{
    uint4 regs[6];
#pragma unroll
    for (int r = 0; r < 6; ++r) {
        int task = tid + r * 512, n = task >> 2, sub = task & 3;
        regs[r] = *(const uint4*)&W[(size_t)n * K + sub * 8];
    }
#pragma unroll
    for (int r = 0; r < 6; ++r) {
        int task = tid + r * 512, n = task >> 2, sub = task & 3;
        *(uint4*)&Wb0[n * WBS + sub * 8] = regs[r];
    }
    __syncthreads();
    for (int c = 0; c < NCH; ++c) {
        unsigned short* cur = (c & 1) ? Wb1 : Wb0;
        unsigned short* nxt = (c & 1) ? Wb0 : Wb1;
        if (c + 1 < NCH) {
#pragma unroll
            for (int r = 0; r < 6; ++r) {
                int task = tid + r * 512, n = task >> 2, sub = task & 3;
                regs[r] = *(const uint4*)&W[(size_t)n * K + (c + 1) * 32 + sub * 8];
            }
        }
        bf16x8 a = *(const bf16x8*)&As[r16 * ast + c * 32 + kq * 8];
#pragma unroll
        for (int f = 0; f < 6; ++f) {
            bf16x8 b = *(const bf16x8*)&cur[(nb[f] + r16) * WBS + kq * 8];
            acc[f] = __builtin_amdgcn_mfma_f32_16x16x32_bf16(a, b, acc[f], 0, 0, 0);
        }
        if (c + 1 < NCH) {
#pragma unroll
            for (int r = 0; r < 6; ++r) {
                int task = tid + r * 512, n = task >> 2, sub = task & 3;
                *(uint4*)&nxt[n * WBS + sub * 8] = regs[r];
            }
        }
        __syncthreads();
    }
}

__global__ __launch_bounds__(512) void k_decoder(
    const float* __restrict__ ctx,
    const unsigned short* __restrict__ Wih,   // (768,768) bf16
    const unsigned short* __restrict__ Whh,   // (768,256) bf16
    const unsigned short* __restrict__ Wfc,   // (768,256) bf16
    const float* __restrict__ b_ih, const float* __restrict__ b_hh,
    const float* __restrict__ b_fc,
    const float* __restrict__ fow, const float* __restrict__ fob,
    float* __restrict__ outp)
{
    __shared__ __align__(16) unsigned short Wb[2][768 * WBS];  // 120 KB
    __shared__ __align__(16) unsigned short inp16[16][776];    // 24.25 KB
    __shared__ __align__(16) unsigned short h16d[16][264];     // 8.25 KB
    __shared__ float red_s[8][16][2];                          // 1 KB

    int tid = threadIdx.x;
    int wv = tid >> 6, l = tid & 63;
    int r0 = blockIdx.x * 16;
    int r16 = l & 15, kq = l >> 4;

    int nbg[6], nbf[6];
    float bih[6], bhh[6], bfc6[6];
#pragma unroll
    for (int f = 0; f < 6; ++f) {
        int g = f >> 1, d = f & 1;
        nbg[f] = g * 256 + wv * 32 + d * 16;
        bih[f] = b_ih[nbg[f] + r16];
        bhh[f] = b_hh[nbg[f] + r16];
        nbf[f] = wv * 96 + f * 16;
        bfc6[f] = b_fc[nbf[f] + r16];
    }
    float fowr[2][2];
#pragma unroll
    for (int o = 0; o < 2; ++o)
#pragma unroll
        for (int d = 0; d < 2; ++d) fowr[o][d] = fow[o * 256 + wv * 32 + d * 16 + r16];
    float fb0 = fob[0], fb1 = fob[1];

    for (int i = tid; i < 16 * 776; i += 512) ((unsigned short*)inp16)[i] = 0;
    for (int i = tid; i < 16 * 256; i += 512) {
        int row = i >> 8, c = i & 255;
        h16d[row][c] = f2bf_(ctx[(size_t)(r0 + row) * H_ + c]);
    }
    float hreg[2][4];
#pragma unroll
    for (int d = 0; d < 2; ++d)
#pragma unroll
        for (int q = 0; q < 4; ++q)
            hreg[d][q] = ctx[(size_t)(r0 + kq * 4 + q) * H_ + wv * 32 + d * 16 + r16];
    __syncthreads();

    for (int t = 0; t < NDAYS; ++t) {
        // ---- gi / gh GEMMs ----
        f32x4 gacc[6], hacc[6];
#pragma unroll
        for (int f = 0; f < 6; ++f) { gacc[f] = (f32x4){0.f,0.f,0.f,0.f}; hacc[f] = (f32x4){0.f,0.f,0.f,0.f}; }
        // t=0: inp == 0 -> gi is bias-only; skip the 24-chunk gi GEMM entirely.
        if (t > 0)
            dec_gemm(Wih, 768, 24, &inp16[0][0], 776, Wb[0], Wb[1], gacc, nbg, tid, r16, kq);
        dec_gemm(Whh, 256,  8, &h16d[0][0], 264, Wb[0], Wb[1], hacc, nbg, tid, r16, kq);
        // ---- GRU cell (lane-local) ----
#pragma unroll
        for (int d = 0; d < 2; ++d)
#pragma unroll
            for (int q = 0; q < 4; ++q) {
                float rr = frcp_(1.f + __expf(-(gacc[d][q] + bih[d] + hacc[d][q] + bhh[d])));
                float zz = frcp_(1.f + __expf(-(gacc[2 + d][q] + bih[2 + d] + hacc[2 + d][q] + bhh[2 + d])));
                float nn = tanhf(fmaf(rr, hacc[4 + d][q] + bhh[4 + d], gacc[4 + d][q] + bih[4 + d]));
                float hnew = (1.f - zz) * nn + zz * hreg[d][q];
                hreg[d][q] = hnew;
                h16d[kq * 4 + q][wv * 32 + d * 16 + r16] = f2bf_(hnew);
            }
        __syncthreads();
        // ---- inp' = relu(h @ Wfc^T + b_fc) ----
        if (t + 1 < NDAYS) {
            f32x4 iacc[6];
#pragma unroll
            for (int f = 0; f < 6; ++f) iacc[f] = (f32x4){0.f,0.f,0.f,0.f};
            dec_gemm(Wfc, 256, 8, &h16d[0][0], 264, Wb[0], Wb[1], iacc, nbf, tid, r16, kq);
#pragma unroll
            for (int f = 0; f < 6; ++f)
#pragma unroll
                for (int q = 0; q < 4; ++q)
                    inp16[kq * 4 + q][nbf[f] + r16] = f2bf_(fmaxf(iacc[f][q] + bfc6[f], 0.f));
        }
        // ---- fc_out: per-wave partials over its 32 cols, LDS reduce ----
        {
            float pq[2][4];
#pragma unroll
            for (int o = 0; o < 2; ++o)
#pragma unroll
                for (int q = 0; q < 4; ++q)
                    pq[o][q] = fmaf(hreg[0][q], fowr[o][0], hreg[1][q] * fowr[o][1]);
#pragma unroll
            for (int o = 0; o < 2; ++o)
#pragma unroll
                for (int q = 0; q < 4; ++q) {
                    float v = pq[o][q];
                    v += __shfl_xor(v, 1, 64); v += __shfl_xor(v, 2, 64);
                    v += __shfl_xor(v, 4, 64); v += __shfl_xor(v, 8, 64);
                    pq[o][q] = v;
                }
            if (r16 == 0) {
#pragma unroll
                for (int q = 0; q < 4; ++q) {
                    red_s[wv][kq * 4 + q][0] = pq[0][q];
                    red_s[wv][kq * 4 + q][1] = pq[1][q];
                }
            }
        }
        __syncthreads();
        if (tid < 16) {
            float l0 = fb0, l1 = fb1;
#pragma unroll
            for (int w = 0; w < 8; ++w) { l0 += red_s[w][tid][0]; l1 += red_s[w][tid][1]; }
            float mx = fmaxf(l0, l1);
            float e0 = __expf(l0 - mx), e1 = __expf(l1 - mx);
            float inv = frcp_(e0 + e1);
            float* op = outp + (size_t)(r0 + tid) * (NDAYS * OUTD) + t * OUTD;
            op[0] = e0 * inv; op[1] = e1 * inv;
        }
        __syncthreads();
    }
}

extern "C" void kernel_launch(void* const* d_in, const int* in_sizes, int n_in,
                              void* d_out, int out_size, void* d_ws, size_t ws_size,
                              hipStream_t stream)
{
    (void)in_sizes; (void)n_in; (void)out_size; (void)ws_size;
    const float* x        = (const float*)d_in[0];
    const int*   len      = (const int*)  d_in[1];
    const float* enc_w_ih = (const float*)d_in[2];
    const float* enc_w_hh = (const float*)d_in[3];
    const float* enc_bias = (const float*)d_in[4];
    const float* dec_w_ih = (const float*)d_in[5];
    const float* dec_w_hh = (const float*)d_in[6];
    const float* dec_b_ih = (const float*)d_in[7];
    const float* dec_b_hh = (const float*)d_in[8];
    const float* attn_w1  = (const float*)d_in[9];
    const float* attn_b1  = (const float*)d_in[10];
    const float* attn_w2  = (const float*)d_in[11];
    const float* attn_b2  = (const float*)d_in[12];
    const float* attn_v   = (const float*)d_in[13];
    const float* attn_bv  = (const float*)d_in[14];
    const float* fc_in_w  = (const float*)d_in[15];
    const float* fc_in_b  = (const float*)d_in[16];
    const float* fc_out_w = (const float*)d_in[17];
    const float* fc_out_b = (const float*)d_in[18];
    const float* span_w   = (const float*)d_in[19];
    const float* span_b   = (const float*)d_in[20];
    float* out = (float*)d_out;
    float* wsf = (float*)d_ws;

    const size_t ROWS = (size_t)B_ * T_;            // 38400
    float* UX    = wsf;                             // 38400*768
    float* Hfull = UX + ROWS * IN_;                 // 38400*256
    float* xs    = Hfull + ROWS * H_;               // 38400
    float* xnb   = xs + ROWS;                       // 38400
    float* WT    = xnb + ROWS;                      // 256*768 floats (packed enc weights)
    float* bvv   = WT + 256 * 768;                  // 768
    float* bvn   = bvv + 768;                       // 16 (3 used)
    float* UXN   = bvn + 16;                        // 38400*3
    float* UXS   = UXN + ROWS * 3;                  // 38400*3
    float* UXP2  = UXS + ROWS * 3;                  // 38400*6
    float* qbuf  = UXP2 + ROWS * 6;                 // 512*256
    float* scb   = qbuf + (size_t)B_ * H_;          // 38400
    float* ctx   = scb + ROWS;                      // 512*256
    float* wpool = ctx + (size_t)B_ * H_;           // bf16 weight pool
    unsigned int* WPK = (unsigned int*)WT;
    unsigned short* Wencbf = (unsigned short*)wpool;                 // 768*768
    unsigned short* W1bf   = Wencbf + (size_t)768 * 768;             // 256*256
    unsigned short* W2bf   = W1bf + (size_t)256 * 256;               // 256*256
    unsigned short* DWIHbf = W2bf + (size_t)256 * 256;               // 768*768
    unsigned short* DWHHbf = DWIHbf + (size_t)768 * 768;             // 768*256
    unsigned short* FCINbf = DWHHbf + (size_t)768 * 256;             // 768*256
    float* S1 = UX;   // reuse after encoder consumes UX

    k_bias<<<1, 256, 0, stream>>>(enc_bias, bvv, bvn);
    k_packw<<<128, 256, 0, stream>>>(enc_w_hh, WPK);
    k_cvt_all<<<(CV5 + 255) / 256, 256, 0, stream>>>(
        enc_w_ih, attn_w1, attn_w2, dec_w_ih, dec_w_hh, fc_in_w,
        Wencbf, W1bf, W2bf, DWIHbf, DWHHbf, FCINbf);
    k_row_scale<<<(unsigned)(ROWS / 4), 256, 0, stream>>>(x, xs, xnb);
    // GEMM writes raw UX + per-gate norm partials; k_uxn turns partials into UXS/UXN.
    k_gemm_ux<<<dim3(4, (unsigned)(ROWS / 128)), 256, 0, stream>>>(x, Wencbf, UX, UXP2);
    k_uxn<<<(unsigned)((ROWS * 3 + 255) / 256), 256, 0, stream>>>(UXP2, xs, xnb, UXS, UXN);
    k_encoder<<<B_ / 2, 512, 0, stream>>>(UX, WPK, bvv, bvn, UXN, UXS, Hfull);
    // Hfull is already logmapped. q = hx @ w2^T + b2 (hx = rows t=T-1, stride T*H)
    k_gemm_mfma_g<<<dim3(H_ / 128, B_ / 128), 256, 0, stream>>>(Hfull + (T_ - 1) * H_, T_ * H_, W2bf, attn_b2, qbuf, H_, H_, 0);
    k_gemm_mfma_g<<<dim3(H_ / 128, (unsigned)(ROWS / 128)), 256, 0, stream>>>(Hfull, H_, W1bf, nullptr, S1, H_, H_, 0);
    k_score<<<(unsigned)(ROWS / 4), 256, 0, stream>>>(S1, qbuf, attn_b1, attn_v, attn_bv, len, scb);
    k_ctx<<<B_, 256, 0, stream>>>(scb, Hfull, span_w, span_b, ctx, out);
    k_decoder<<<B_ / 16, 512, 0, stream>>>(ctx, DWIHbf, DWHHbf, FCINbf,
                                           dec_b_ih, dec_b_hh, fc_in_b,
                                           fc_out_w, fc_out_b, out + B_ * NSPAN);
}

// Round 22
// 1250.722 us; speedup vs baseline: 1.1576x; 1.0460x over previous
//
#include <hip/hip_runtime.h>
#include <hip/hip_fp16.h>
#include <math.h>

#define B_    512
#define T_    75
#define IN_   768
#define H_    256
#define NSPAN 8
#define OUTD  2
#define NDAYS 10
#define EPS_  1e-5f
#define MAXN_ 0.999f
#define CLIP_ (1.0f - 1e-7f)

typedef short bf16x8 __attribute__((ext_vector_type(8)));
typedef float f32x4 __attribute__((ext_vector_type(4)));

// ---------------- wave helpers (wave = 64 lanes) ----------------
// DPP-based wave reduction: VALU pipe instead of ds_swizzle.
template<int CTRL, int RMASK>
__device__ __forceinline__ float dppadd_(float v) {
    return v + __int_as_float(__builtin_amdgcn_update_dpp(
        0, __float_as_int(v), CTRL, RMASK, 0xf, true));
}
__device__ __forceinline__ float wred(float v) {
    v = dppadd_<0x111, 0xf>(v);   // row_shr:1
    v = dppadd_<0x112, 0xf>(v);   // row_shr:2
    v = dppadd_<0x114, 0xf>(v);   // row_shr:4
    v = dppadd_<0x118, 0xf>(v);   // row_shr:8
    v = dppadd_<0x142, 0xa>(v);   // row_bcast:15
    v = dppadd_<0x143, 0xc>(v);   // row_bcast:31; lane63 = total
    return __int_as_float(__builtin_amdgcn_readlane(__float_as_int(v), 63));
}
__device__ __forceinline__ float artanh_(float x) {
    x = fminf(x, CLIP_);
    return 0.5f * logf((1.f + x) / (1.f - x));
}
__device__ __forceinline__ float sigm_(float x) { return 1.f / (1.f + expf(-x)); }
__device__ __forceinline__ float h2f_(unsigned short u) {
    union { unsigned short us; __half h; } cv; cv.us = u;
    return __half2float(cv.h);
}
__device__ __forceinline__ unsigned int packf16(float a, float b) {
    union { __half h; unsigned short us; } ca, cb;
    ca.h = __float2half(a); cb.h = __float2half(b);
    return (unsigned int)ca.us | ((unsigned int)cb.us << 16);
}
__device__ __forceinline__ unsigned short f2bf_(float f) {  // RNE f32->bf16
    union { float f; unsigned u; } c; c.f = f;
    unsigned r = c.u + 0x7fff + ((c.u >> 16) & 1);
    return (unsigned short)(r >> 16);
}
// f16-pair dot product with f32 accumulator
__device__ __forceinline__ float dot2_(unsigned int w, unsigned int h, float acc) {
#if __has_builtin(__builtin_amdgcn_fdot2)
    typedef _Float16 h2_t __attribute__((ext_vector_type(2)));
    union { unsigned int u; h2_t v; } a, b;
    a.u = w; b.u = h;
    return __builtin_amdgcn_fdot2(a.v, b.v, acc, false);
#else
    float wx = h2f_((unsigned short)(w & 0xffff)), wy = h2f_((unsigned short)(w >> 16));
    float hx = h2f_((unsigned short)(h & 0xffff)), hy = h2f_((unsigned short)(h >> 16));
    return fmaf(wy, hy, fmaf(wx, hx, acc));
#endif
}
// ---- fast-math (encoder hot path). Args are wave-uniform norms >= 0. ----
__device__ __forceinline__ float frcp_(float x) { return __builtin_amdgcn_rcpf(x); }
__device__ __forceinline__ float tanh_f(float x) {
    if (x < 0.01f) return x * (1.f - 0.33333334f * x * x);
    return 1.f - 2.f * frcp_(__expf(2.f * x) + 1.f);
}
__device__ __forceinline__ float artanh_f(float x) {
    x = fminf(x, CLIP_);
    if (x < 0.01f) return x * (1.f + 0.33333334f * x * x);
    return 0.5f * __logf((1.f + x) * frcp_(1.f - x));
}

// -------- norm-carrying mobius primitives (wave owns 256-vec, 4/lane) --------
__device__ __forceinline__ float wsum4(const float* v) {
    float ss = 0.f;
#pragma unroll
    for (int q = 0; q < 4; ++q) ss = fmaf(v[q], v[q], ss);
    return wred(ss);
}
__device__ __forceinline__ float mvf_n(float* v, float xn_raw) {
    float n = fmaxf(sqrtf(fmaxf(wsum4(v), 1e-15f)), EPS_);
    float xc = fmaxf(xn_raw, EPS_);
    float tt = tanh_f(n * frcp_(xc) * artanh_f(xc));
    float sc = tt * frcp_(n);
    float outn = tt;
    if (tt > MAXN_) { sc = MAXN_ * frcp_(n); outn = MAXN_; }
#pragma unroll
    for (int q = 0; q < 4; ++q) v[q] *= sc;
    return outn;
}
__device__ __forceinline__ float madd_n(float* x, const float* y, float x2, float y2) {
    float xy = 0.f;
#pragma unroll
    for (int q = 0; q < 4; ++q) xy = fmaf(x[q], y[q], xy);
    xy = wred(xy);
    float den = fmaxf(1.f + 2.f * xy + x2 * y2, EPS_);
    float cx = 1.f + 2.f * xy + y2, cy = 1.f - x2;
#pragma unroll
    for (int q = 0; q < 4; ++q) x[q] = cx * x[q] + cy * y[q];
    float nn = fmaf(cx * cx, x2, fmaf(2.f * cx * cy, xy, cy * cy * y2));
    float inv = frcp_(den);
    float pn = sqrtf(fmaxf(nn, 1e-15f)) * inv;
    float s = inv, outn = pn;
    if (pn > MAXN_) { s *= MAXN_ * frcp_(pn); outn = MAXN_; }
#pragma unroll
    for (int q = 0; q < 4; ++q) x[q] *= s;
    return outn;
}
__device__ __forceinline__ void lsig_n(float* v, float n_raw) {
    float nc = fmaxf(n_raw, EPS_);
    float s = artanh_f(nc) * frcp_(nc);
#pragma unroll
    for (int q = 0; q < 4; ++q) v[q] = frcp_(1.f + __expf(-v[q] * s));
}
__device__ __forceinline__ float pmul_n(const float* w, const float* x, float* o, float xn_raw) {
    float xc = fmaxf(xn_raw, EPS_);
#pragma unroll
    for (int q = 0; q < 4; ++q) o[q] = w[q] * x[q];
    float wxn = fmaxf(sqrtf(fmaxf(wsum4(o), 1e-15f)), EPS_);
    float tt = tanh_f(wxn * frcp_(xc) * artanh_f(xc));
    float sc = tt * frcp_(wxn);
    float outn = tt;
    if (tt > MAXN_) { sc = MAXN_ * frcp_(wxn); outn = MAXN_; }
#pragma unroll
    for (int q = 0; q < 4; ++q) o[q] *= sc;
    return outn;
}

// ---------------- prep kernels ----------------
__global__ __launch_bounds__(256) void k_bias(const float* __restrict__ eb, float* __restrict__ bv,
                                              float* __restrict__ bvn) {
    int wid = threadIdx.x >> 6, lane = threadIdx.x & 63;
    if (wid >= 3) return;
    const float* p = eb + wid * H_;
    float v0 = p[lane], v1 = p[lane + 64], v2 = p[lane + 128], v3 = p[lane + 192];
    float ss = wred(v0 * v0 + v1 * v1 + v2 * v2 + v3 * v3);
    float n = sqrtf(fmaxf(ss, 1e-15f));
    float nc = fmaxf(n, EPS_);
    float s = tanhf(nc) / nc;
    float nv = n * s;
    float fn = nv;
    if (nv > MAXN_) { s *= MAXN_ / nv; fn = MAXN_; }
    bv[wid * H_ + lane] = v0 * s;
    bv[wid * H_ + lane + 64] = v1 * s;
    bv[wid * H_ + lane + 128] = v2 * s;
    bv[wid * H_ + lane + 192] = v3 * s;
    if (lane == 0) bvn[wid] = fn;
}

__global__ __launch_bounds__(256) void k_packw(const float* __restrict__ whh, unsigned int* __restrict__ WPK) {
    int kp = blockIdx.x;
    for (int j = threadIdx.x; j < 768; j += 256) {
        float w0 = whh[(size_t)j * 256 + 2 * kp];
        float w1 = whh[(size_t)j * 256 + 2 * kp + 1];
        WPK[(size_t)kp * 768 + j] = packf16(w0, w1);
    }
}

// merged f32 -> bf16 conversion over 6 weight regions (saves 5 launches)
#define CV0 147456   // enc_w_ih  768*768/4
#define CV1 163840   // + attn_w1 256*256/4
#define CV2 180224   // + attn_w2
#define CV3 327680   // + dec_w_ih 768*768/4
#define CV4 376832   // + dec_w_hh 768*256/4
#define CV5 425984   // + fc_in_w  768*256/4
__global__ __launch_bounds__(256) void k_cvt_all(
    const float* __restrict__ s0, const float* __restrict__ s1, const float* __restrict__ s2,
    const float* __restrict__ s3, const float* __restrict__ s4, const float* __restrict__ s5,
    unsigned short* __restrict__ d0, unsigned short* __restrict__ d1, unsigned short* __restrict__ d2,
    unsigned short* __restrict__ d3, unsigned short* __restrict__ d4, unsigned short* __restrict__ d5)
{
    int i = blockIdx.x * 256 + threadIdx.x;
    if (i >= CV5) return;
    const float* src; unsigned short* dst; int off;
    if      (i < CV0) { src = s0; dst = d0; off = i; }
    else if (i < CV1) { src = s1; dst = d1; off = i - CV0; }
    else if (i < CV2) { src = s2; dst = d2; off = i - CV1; }
    else if (i < CV3) { src = s3; dst = d3; off = i - CV2; }
    else if (i < CV4) { src = s4; dst = d4; off = i - CV3; }
    else              { src = s5; dst = d5; off = i - CV4; }
    float4 v = *(const float4*)&src[(size_t)off * 4];
    ushort4 o;
    o.x = f2bf_(v.x); o.y = f2bf_(v.y); o.z = f2bf_(v.z); o.w = f2bf_(v.w);
    *(ushort4*)&dst[(size_t)off * 4] = o;
}

// combine per-gate norm partials -> per-(row,gate) scale UXS and final norm UXN
__global__ __launch_bounds__(256) void k_uxn(
    const float* __restrict__ UXP2, const float* __restrict__ xs, const float* __restrict__ xnb,
    float* __restrict__ UXS, float* __restrict__ UXN)
{
    int rg = blockIdx.x * 256 + threadIdx.x;
    if (rg >= 38400 * 3) return;
    int row = rg / 3, g = rg - row * 3;
    float ss = UXP2[(size_t)row * 6 + g * 2] + UXP2[(size_t)row * 6 + g * 2 + 1];
    float s = xs[row], xv = xnb[row];
    float ssc = s * s * ss;
    float mxn = fmaxf(sqrtf(fmaxf(ssc, 1e-15f)), EPS_);
    float tt = tanhf(mxn / xv * artanh_(xv));
    float sc = tt / mxn;
    float fn = tt;
    if (tt > MAXN_) { sc = MAXN_ / mxn; fn = MAXN_; }
    UXS[rg] = s * sc;
    UXN[rg] = fn;
}

// ---------------- MFMA bf16 GEMM (192-N tile) + per-gate norm partials + row norm (UX path) ----------------
// Writes raw C = x @ Wenc^T, per-(row,gate) sum-of-squares partials into fixed slots,
// AND (nt==0 blocks only) the expmap0 row scale xs / norm xnb computed from the A loads:
// lane (r16,kq) covers k = k0+kq*8..+7 over the K loop -> full row across the 4 kq lanes.
__global__ __launch_bounds__(256) void k_gemm_ux(
    const float* __restrict__ A, const unsigned short* __restrict__ Wbf,
    float* __restrict__ C, float* __restrict__ UXP2,
    float* __restrict__ xs, float* __restrict__ xnb)
{
    int wv = threadIdx.x >> 6, l = threadIdx.x & 63;
    int m0 = blockIdx.y * 128 + wv * 32;
    int nt = blockIdx.x;
    int n0 = nt * 192;
    int r16 = l & 15, kq = l >> 4;
    f32x4 acc[2][12];
#pragma unroll
    for (int i = 0; i < 2; ++i)
#pragma unroll
        for (int j = 0; j < 12; ++j) acc[i][j] = (f32x4){0.f, 0.f, 0.f, 0.f};
    float ssr[2] = {0.f, 0.f};

    for (int k0 = 0; k0 < IN_; k0 += 32) {
        bf16x8 af[2];
#pragma unroll
        for (int mi = 0; mi < 2; ++mi) {
            const float* ap = A + (size_t)(m0 + mi * 16 + r16) * IN_ + k0 + kq * 8;
            float4 x0 = *(const float4*)ap;
            float4 x1 = *(const float4*)(ap + 4);
            ssr[mi] = fmaf(x0.x, x0.x, ssr[mi]); ssr[mi] = fmaf(x0.y, x0.y, ssr[mi]);
            ssr[mi] = fmaf(x0.z, x0.z, ssr[mi]); ssr[mi] = fmaf(x0.w, x0.w, ssr[mi]);
            ssr[mi] = fmaf(x1.x, x1.x, ssr[mi]); ssr[mi] = fmaf(x1.y, x1.y, ssr[mi]);
            ssr[mi] = fmaf(x1.z, x1.z, ssr[mi]); ssr[mi] = fmaf(x1.w, x1.w, ssr[mi]);
            af[mi][0] = (short)f2bf_(x0.x); af[mi][1] = (short)f2bf_(x0.y);
            af[mi][2] = (short)f2bf_(x0.z); af[mi][3] = (short)f2bf_(x0.w);
            af[mi][4] = (short)f2bf_(x1.x); af[mi][5] = (short)f2bf_(x1.y);
            af[mi][6] = (short)f2bf_(x1.z); af[mi][7] = (short)f2bf_(x1.w);
        }
#pragma unroll
        for (int nj = 0; nj < 12; ++nj) {
            bf16x8 bf = *(const bf16x8*)(Wbf + (size_t)(n0 + nj * 16 + r16) * IN_ + k0 + kq * 8);
            acc[0][nj] = __builtin_amdgcn_mfma_f32_16x16x32_bf16(af[0], bf, acc[0][nj], 0, 0, 0);
            acc[1][nj] = __builtin_amdgcn_mfma_f32_16x16x32_bf16(af[1], bf, acc[1][nj], 0, 0, 0);
        }
    }
    // raw C write
#pragma unroll
    for (int mi = 0; mi < 2; ++mi)
#pragma unroll
        for (int nj = 0; nj < 12; ++nj)
#pragma unroll
            for (int q = 0; q < 4; ++q)
                C[(size_t)(m0 + mi * 16 + kq * 4 + q) * IN_ + n0 + nj * 16 + r16] = acc[mi][nj][q];
    // expmap0 row scale (nt==0 blocks own the write; others computed identical partials)
    if (nt == 0) {
#pragma unroll
        for (int mi = 0; mi < 2; ++mi) {
            float ss = ssr[mi];
            ss += __shfl_xor(ss, 16, 64);
            ss += __shfl_xor(ss, 32, 64);
            if (kq == 0) {
                int row = m0 + mi * 16 + r16;
                float n = sqrtf(fmaxf(ss, 1e-15f));
                float nc = fmaxf(n, EPS_);
                float s = tanhf(nc) / nc;
                float nv = n * s;
                if (nv > MAXN_) s *= MAXN_ / nv;
                xs[row] = s;
                xnb[row] = fmaxf(n * s, EPS_);
            }
        }
    }
    // per-gate norm partials
    int split, idxA, idxB;
    if      (nt == 0) { split = 12; idxA = 0;  idxB = -1; }
    else if (nt == 1) { split = 4;  idxA = 1;  idxB = 2;  }
    else if (nt == 2) { split = 8;  idxA = 3;  idxB = 4;  }
    else              { split = 0;  idxA = -1; idxB = 5;  }
#pragma unroll
    for (int mi = 0; mi < 2; ++mi)
#pragma unroll
        for (int q = 0; q < 4; ++q) {
            int row = m0 + mi * 16 + kq * 4 + q;
            float ssA = 0.f, ssB = 0.f;
#pragma unroll
            for (int nj = 0; nj < 12; ++nj) {
                float v = acc[mi][nj][q];
                if (nj < split) ssA = fmaf(v, v, ssA);
                else            ssB = fmaf(v, v, ssB);
            }
            ssA += __shfl_xor(ssA, 1, 64); ssA += __shfl_xor(ssA, 2, 64);
            ssA += __shfl_xor(ssA, 4, 64); ssA += __shfl_xor(ssA, 8, 64);
            ssB += __shfl_xor(ssB, 1, 64); ssB += __shfl_xor(ssB, 2, 64);
            ssB += __shfl_xor(ssB, 4, 64); ssB += __shfl_xor(ssB, 8, 64);
            if (r16 == 0) {
                if (idxA >= 0) UXP2[(size_t)row * 6 + idxA] = ssA;
                if (idxB >= 0) UXP2[(size_t)row * 6 + idxB] = ssB;
            }
        }
}

// ---------------- general MFMA bf16 GEMM (128-N tile): C = A @ Wbf^T (+bias)(+relu) ----------------
__global__ __launch_bounds__(256) void k_gemm_mfma_g(
    const float* __restrict__ A, int lda,
    const unsigned short* __restrict__ Wbf,
    const float* __restrict__ bias,
    float* __restrict__ C, int N, int K, int act)
{
    int wv = threadIdx.x >> 6, l = threadIdx.x & 63;
    int m0 = blockIdx.y * 128 + wv * 32;
    int n0 = blockIdx.x * 128;
    int r16 = l & 15, kq = l >> 4;
    f32x4 acc[2][8];
#pragma unroll
    for (int i = 0; i < 2; ++i)
#pragma unroll
        for (int j = 0; j < 8; ++j) acc[i][j] = (f32x4){0.f, 0.f, 0.f, 0.f};

    for (int k0 = 0; k0 < K; k0 += 32) {
        bf16x8 af[2];
#pragma unroll
        for (int mi = 0; mi < 2; ++mi) {
            const float* ap = A + (size_t)(m0 + mi * 16 + r16) * lda + k0 + kq * 8;
            float4 x0 = *(const float4*)ap;
            float4 x1 = *(const float4*)(ap + 4);
            af[mi][0] = (short)f2bf_(x0.x); af[mi][1] = (short)f2bf_(x0.y);
            af[mi][2] = (short)f2bf_(x0.z); af[mi][3] = (short)f2bf_(x0.w);
            af[mi][4] = (short)f2bf_(x1.x); af[mi][5] = (short)f2bf_(x1.y);
            af[mi][6] = (short)f2bf_(x1.z); af[mi][7] = (short)f2bf_(x1.w);
        }
#pragma unroll
        for (int nj = 0; nj < 8; ++nj) {
            bf16x8 bf = *(const bf16x8*)(Wbf + (size_t)(n0 + nj * 16 + r16) * K + k0 + kq * 8);
            acc[0][nj] = __builtin_amdgcn_mfma_f32_16x16x32_bf16(af[0], bf, acc[0][nj], 0, 0, 0);
            acc[1][nj] = __builtin_amdgcn_mfma_f32_16x16x32_bf16(af[1], bf, acc[1][nj], 0, 0, 0);
        }
    }
#pragma unroll
    for (int mi = 0; mi < 2; ++mi)
#pragma unroll
        for (int nj = 0; nj < 8; ++nj) {
            int col = n0 + nj * 16 + r16;
            float bb = bias ? bias[col] : 0.f;
#pragma unroll
            for (int q = 0; q < 4; ++q) {
                float v = acc[mi][nj][q] + bb;
                if (act) v = fmaxf(v, 0.f);
                C[(size_t)(m0 + mi * 16 + kq * 4 + q) * N + col] = v;
            }
        }
}

// ---------------- mobius GRU encoder v12: R11 structure + UXS scale-at-load ----------------
__global__ __launch_bounds__(512) void k_encoder(
    const float* __restrict__ UX, const unsigned int* __restrict__ WPK,
    const float* __restrict__ bv, const float* __restrict__ bvn,
    const float* __restrict__ UXN, const float* __restrict__ UXS,
    float* __restrict__ Hfull)
{
    __shared__ __align__(16) unsigned int h16u[2][128];
    __shared__ __align__(16) unsigned int c16u[2][128];
    __shared__ float P1[2][512];
    __shared__ float P2[2][2][256];
    __shared__ float bias_s[3][256];
    __shared__ float zbuf[2][256];
    __shared__ float hns[2];

    int tid = threadIdx.x;
    int wid = tid >> 6, lane = tid & 63;
    int b0 = blockIdx.x * 2;

    for (int i = tid; i < 768; i += 512) bias_s[i >> 8][i & 255] = bv[i];
    if (tid < 256) h16u[tid >> 7][tid & 127] = 0u;
    if (tid < 2) hns[tid] = 0.f;
    __syncthreads();

    float bn0 = bvn[0], bn1 = bvn[1], bn2 = bvn[2];

    int j1 = (tid < 256) ? tid : (tid + 256);
    unsigned int wA[128];
#pragma unroll
    for (int kp = 0; kp < 128; ++kp) wA[kp] = WPK[(size_t)kp * 768 + j1];
    int j2i = tid & 255;
    int half = tid >> 8;
    int kb2 = half * 64;
    unsigned int wB[64];
#pragma unroll
    for (int i = 0; i < 64; ++i) wB[i] = WPK[(size_t)(kb2 + i) * 768 + 256 + j2i];

    float hreg[4] = {0.f, 0.f, 0.f, 0.f};
    float hn_c = 0.f;
    float rhn_c = 0.f;

    for (int t = 0; t < T_; ++t) {
        float uxp_a[4], uxp_b[4];
        float uxn_a = 0.f, uxn_b = 0.f;
        if (wid < 2) {
            const float* uxr = UX + ((size_t)(b0 + wid) * T_ + t) * IN_;
            size_t rg3 = ((size_t)(b0 + wid) * T_ + t) * 3;
            float sa = UXS[rg3], sb = UXS[rg3 + 1];
            float4 u0 = *(const float4*)&uxr[4 * lane];
            float4 u1 = *(const float4*)&uxr[256 + 4 * lane];
            uxp_a[0] = u0.x * sa; uxp_a[1] = u0.y * sa; uxp_a[2] = u0.z * sa; uxp_a[3] = u0.w * sa;
            uxp_b[0] = u1.x * sb; uxp_b[1] = u1.y * sb; uxp_b[2] = u1.z * sb; uxp_b[3] = u1.w * sb;
            uxn_a = UXN[rg3]; uxn_b = UXN[rg3 + 1];
        } else if (wid < 4) {
            int row = wid - 2;
            const float* uxr = UX + ((size_t)(b0 + row) * T_ + t) * IN_;
            size_t rg3 = ((size_t)(b0 + row) * T_ + t) * 3;
            float sz = UXS[rg3 + 2];
            float4 u2 = *(const float4*)&uxr[512 + 4 * lane];
            uxp_a[0] = u2.x * sz; uxp_a[1] = u2.y * sz; uxp_a[2] = u2.z * sz; uxp_a[3] = u2.w * sz;
            uxn_a = UXN[rg3 + 2];
        }

        {
            float a0 = 0.f, a1 = 0.f;
#pragma unroll
            for (int q = 0; q < 32; ++q) {
                uint4 hv0 = *(const uint4*)&h16u[0][q * 4];
                uint4 hv1 = *(const uint4*)&h16u[1][q * 4];
                a0 = dot2_(wA[q * 4 + 0], hv0.x, a0);
                a0 = dot2_(wA[q * 4 + 1], hv0.y, a0);
                a0 = dot2_(wA[q * 4 + 2], hv0.z, a0);
                a0 = dot2_(wA[q * 4 + 3], hv0.w, a0);
                a1 = dot2_(wA[q * 4 + 0], hv1.x, a1);
                a1 = dot2_(wA[q * 4 + 1], hv1.y, a1);
                a1 = dot2_(wA[q * 4 + 2], hv1.z, a1);
                a1 = dot2_(wA[q * 4 + 3], hv1.w, a1);
            }
            P1[0][tid] = a0;
            P1[1][tid] = a1;
        }
        __syncthreads();

        if (wid < 2) {
            int row = wid;
            float rr[4], tmp[4];
            float4 pr = *(const float4*)&P1[row][4 * lane];
            rr[0] = pr.x; rr[1] = pr.y; rr[2] = pr.z; rr[3] = pr.w;
            float rn = mvf_n(rr, hn_c);
            float n1 = madd_n(rr, uxp_a, rn * rn, uxn_a * uxn_a);
            {
                float4 br = *(const float4*)&bias_s[0][4 * lane];
                tmp[0] = br.x; tmp[1] = br.y; tmp[2] = br.z; tmp[3] = br.w;
            }
            float n2 = madd_n(rr, tmp, n1 * n1, bn0 * bn0);
            lsig_n(rr, n2);
            float rh[4];
            rhn_c = pmul_n(rr, hreg, rh, hn_c);
            c16u[row][2 * lane]     = packf16(rh[0], rh[1]);
            c16u[row][2 * lane + 1] = packf16(rh[2], rh[3]);
        } else if (wid < 4) {
            int row = wid - 2;
            float zr[4], tmp[4];
            float4 pz = *(const float4*)&P1[row][256 + 4 * lane];
            zr[0] = pz.x; zr[1] = pz.y; zr[2] = pz.z; zr[3] = pz.w;
            float hn_l = hns[row];
            float zn = mvf_n(zr, hn_l);
            float n1 = madd_n(zr, uxp_a, zn * zn, uxn_a * uxn_a);
            {
                float4 bz = *(const float4*)&bias_s[2][4 * lane];
                tmp[0] = bz.x; tmp[1] = bz.y; tmp[2] = bz.z; tmp[3] = bz.w;
            }
            float n2 = madd_n(zr, tmp, n1 * n1, bn2 * bn2);
            lsig_n(zr, n2);
            *(float4*)&zbuf[row][4 * lane] = make_float4(zr[0], zr[1], zr[2], zr[3]);
        }
        __syncthreads();

        {
            float c0 = 0.f, c1 = 0.f;
#pragma unroll
            for (int q = 0; q < 16; ++q) {
                uint4 cv0 = *(const uint4*)&c16u[0][kb2 + q * 4];
                uint4 cv1 = *(const uint4*)&c16u[1][kb2 + q * 4];
                c0 = dot2_(wB[q * 4 + 0], cv0.x, c0);
                c0 = dot2_(wB[q * 4 + 1], cv0.y, c0);
                c0 = dot2_(wB[q * 4 + 2], cv0.z, c0);
                c0 = dot2_(wB[q * 4 + 3], cv0.w, c0);
                c1 = dot2_(wB[q * 4 + 0], cv1.x, c1);
                c1 = dot2_(wB[q * 4 + 1], cv1.y, c1);
                c1 = dot2_(wB[q * 4 + 2], cv1.z, c1);
                c1 = dot2_(wB[q * 4 + 3], cv1.w, c1);
            }
            P2[half][0][j2i] = c0;
            P2[half][1][j2i] = c1;
        }
        __syncthreads();

        if (wid < 2) {
            int row = wid;
            float ht[4], tmp[4];
            float4 p0 = *(const float4*)&P2[0][row][4 * lane];
            float4 p1 = *(const float4*)&P2[1][row][4 * lane];
            ht[0] = p0.x + p1.x; ht[1] = p0.y + p1.y;
            ht[2] = p0.z + p1.z; ht[3] = p0.w + p1.w;
            float htn = mvf_n(ht, rhn_c);
            float n1 = madd_n(ht, uxp_b, htn * htn, uxn_b * uxn_b);
            {
                float4 bh = *(const float4*)&bias_s[1][4 * lane];
                tmp[0] = bh.x; tmp[1] = bh.y; tmp[2] = bh.z; tmp[3] = bh.w;
            }
            float n2 = madd_n(ht, tmp, n1 * n1, bn1 * bn1);
            float dl[4];
#pragma unroll
            for (int q = 0; q < 4; ++q) dl[q] = -hreg[q];
            float dn = madd_n(dl, ht, hn_c * hn_c, n2 * n2);
            float zv[4];
            {
                float4 zl = *(const float4*)&zbuf[row][4 * lane];
                zv[0] = zl.x; zv[1] = zl.y; zv[2] = zl.z; zv[3] = zl.w;
            }
            float dv[4];
            float dvn = pmul_n(zv, dl, dv, dn);
            float hn_new = madd_n(hreg, dv, hn_c * hn_c, dvn * dvn);
            hn_c = hn_new;
            float ncl = fmaxf(hn_new, EPS_);
            float ls = artanh_f(ncl) * frcp_(ncl);
            float* orow = Hfull + ((size_t)(b0 + row) * T_ + t) * H_;
            *(float4*)&orow[4 * lane] = make_float4(hreg[0] * ls, hreg[1] * ls, hreg[2] * ls, hreg[3] * ls);
            h16u[row][2 * lane]     = packf16(hreg[0], hreg[1]);
            h16u[row][2 * lane + 1] = packf16(hreg[2], hreg[3]);
            if (lane == 0) hns[row] = hn_new;
        }
        __syncthreads();
    }
}

// score[b,t] = v . tanh(S1 + b1 + q[b]) + bv, masked
__global__ __launch_bounds__(256) void k_score(
    const float* __restrict__ S1, const float* __restrict__ q,
    const float* __restrict__ b1, const float* __restrict__ av,
    const float* __restrict__ abv, const int* __restrict__ len,
    float* __restrict__ sc)
{
    int wid = threadIdx.x >> 6, lane = threadIdx.x & 63;
    int row = blockIdx.x * 4 + wid;
    int b = row / T_, t = row - b * T_;
    const float* s1 = S1 + (size_t)row * H_;
    const float* qp = q + (size_t)b * H_;
    float part = 0.f;
#pragma unroll
    for (int qq = 0; qq < 4; ++qq) {
        int j = lane + 64 * qq;
        float u = tanhf(s1[j] + b1[j] + qp[j]);
        part = fmaf(u, av[j], part);
    }
    part = wred(part) + abv[0];
    if (t >= len[b]) part = -1e9f;
    if (lane == 0) sc[row] = part;
}

// per-b: softmax over T, ctx = sum w*full, span logits + softmax -> d_out
__global__ __launch_bounds__(256) void k_ctx(
    const float* __restrict__ sc, const float* __restrict__ full,
    const float* __restrict__ spw, const float* __restrict__ spb,
    float* __restrict__ ctx, float* __restrict__ outsp)
{
    int b = blockIdx.x, tid = threadIdx.x;
    __shared__ float w_s[T_];
    __shared__ float cs[H_];
    __shared__ float red[NSPAN];
    if (tid < T_) w_s[tid] = sc[b * T_ + tid];
    __syncthreads();
    if (tid == 0) {
        float mx = -1e30f;
        for (int t = 0; t < T_; ++t) mx = fmaxf(mx, w_s[t]);
        float sum = 0.f;
        for (int t = 0; t < T_; ++t) { float e = expf(w_s[t] - mx); w_s[t] = e; sum += e; }
        float inv = 1.f / sum;
        for (int t = 0; t < T_; ++t) w_s[t] *= inv;
    }
    __syncthreads();
    float c = 0.f;
    for (int t = 0; t < T_; ++t) c = fmaf(w_s[t], full[((size_t)b * T_ + t) * H_ + tid], c);
    ctx[(size_t)b * H_ + tid] = c;
    cs[tid] = c;
    __syncthreads();
    if (tid < NSPAN) {
        float lg = spb[tid];
        for (int j = 0; j < H_; ++j) lg = fmaf(spw[tid * H_ + j], cs[j], lg);
        red[tid] = lg;
    }
    __syncthreads();
    if (tid == 0) {
        float mx = red[0];
        for (int k2 = 1; k2 < NSPAN; ++k2) mx = fmaxf(mx, red[k2]);
        float sum = 0.f;
        for (int k2 = 0; k2 < NSPAN; ++k2) sum += expf(red[k2] - mx);
        float inv = 1.f / sum;
        for (int k2 = 0; k2 < NSPAN; ++k2) outsp[(size_t)b * NSPAN + k2] = expf(red[k2] - mx) * inv;
    }
}

// ---------------- decoder v2 (R18 exact): LDS-staged weights, gate-aligned wave columns ----------------
#define WBS 40   // padded chunk row stride in ushorts (32 used + 8 pad; 80B, 16B-aligned)
__device__ __forceinline__ void dec_gemm(
    const unsigned short* __restrict__ W, int K, int NCH,
    const unsigned short* As, int ast,
    unsigned short* Wb0, unsigned short* Wb1,
    f32x4 acc[6], const int nb[6],
    int tid, int r16, int kq)
{
    uint4 regs[6];
#pragma unroll
    for (int r = 0; r < 6; ++r) {
        int task = tid + r * 512, n = task >> 2, sub = task & 3;
        regs[r] = *(const uint4*)&W[(size_t)n * K + sub * 8];
    }
#pragma unroll
    for (int r = 0; r < 6; ++r) {
        int task = tid + r * 512, n = task >> 2, sub = task & 3;
        *(uint4*)&Wb0[n * WBS + sub * 8] = regs[r];
    }
    __syncthreads();
    for (int c = 0; c < NCH; ++c) {
        unsigned short* cur = (c & 1) ? Wb1 : Wb0;
        unsigned short* nxt = (c & 1) ? Wb0 : Wb1;
        if (c + 1 < NCH) {
#pragma unroll
            for (int r = 0; r < 6; ++r) {
                int task = tid + r * 512, n = task >> 2, sub = task & 3;
                regs[r] = *(const uint4*)&W[(size_t)n * K + (c + 1) * 32 + sub * 8];
            }
        }
        bf16x8 a = *(const bf16x8*)&As[r16 * ast + c * 32 + kq * 8];
#pragma unroll
        for (int f = 0; f < 6; ++f) {
            bf16x8 b = *(const bf16x8*)&cur[(nb[f] + r16) * WBS + kq * 8];
            acc[f] = __builtin_amdgcn_mfma_f32_16x16x32_bf16(a, b, acc[f], 0, 0, 0);
        }
        if (c + 1 < NCH) {
#pragma unroll
            for (int r = 0; r < 6; ++r) {
                int task = tid + r * 512, n = task >> 2, sub = task & 3;
                *(uint4*)&nxt[n * WBS + sub * 8] = regs[r];
            }
        }
        __syncthreads();
    }
}

__global__ __launch_bounds__(512) void k_decoder(
    const float* __restrict__ ctx,
    const unsigned short* __restrict__ Wih,   // (768,768) bf16
    const unsigned short* __restrict__ Whh,   // (768,256) bf16
    const unsigned short* __restrict__ Wfc,   // (768,256) bf16
    const float* __restrict__ b_ih, const float* __restrict__ b_hh,
    const float* __restrict__ b_fc,
    const float* __restrict__ fow, const float* __restrict__ fob,
    float* __restrict__ outp)
{
    __shared__ __align__(16) unsigned short Wb[2][768 * WBS];  // 120 KB
    __shared__ __align__(16) unsigned short inp16[16][776];    // 24.25 KB
    __shared__ __align__(16) unsigned short h16d[16][264];     // 8.25 KB
    __shared__ float red_s[8][16][2];                          // 1 KB

    int tid = threadIdx.x;
    int wv = tid >> 6, l = tid & 63;
    int r0 = blockIdx.x * 16;
    int r16 = l & 15, kq = l >> 4;

    int nbg[6], nbf[6];
    float bih[6], bhh[6], bfc6[6];
#pragma unroll
    for (int f = 0; f < 6; ++f) {
        int g = f >> 1, d = f & 1;
        nbg[f] = g * 256 + wv * 32 + d * 16;
        bih[f] = b_ih[nbg[f] + r16];
        bhh[f] = b_hh[nbg[f] + r16];
        nbf[f] = wv * 96 + f * 16;
        bfc6[f] = b_fc[nbf[f] + r16];
    }
    float fowr[2][2];
#pragma unroll
    for (int o = 0; o < 2; ++o)
#pragma unroll
        for (int d = 0; d < 2; ++d) fowr[o][d] = fow[o * 256 + wv * 32 + d * 16 + r16];
    float fb0 = fob[0], fb1 = fob[1];

    for (int i = tid; i < 16 * 776; i += 512) ((unsigned short*)inp16)[i] = 0;
    for (int i = tid; i < 16 * 256; i += 512) {
        int row = i >> 8, c = i & 255;
        h16d[row][c] = f2bf_(ctx[(size_t)(r0 + row) * H_ + c]);
    }
    float hreg[2][4];
#pragma unroll
    for (int d = 0; d < 2; ++d)
#pragma unroll
        for (int q = 0; q < 4; ++q)
            hreg[d][q] = ctx[(size_t)(r0 + kq * 4 + q) * H_ + wv * 32 + d * 16 + r16];
    __syncthreads();

    for (int t = 0; t < NDAYS; ++t) {
        // ---- gi / gh GEMMs ----
        f32x4 gacc[6], hacc[6];
#pragma unroll
        for (int f = 0; f < 6; ++f) { gacc[f] = (f32x4){0.f,0.f,0.f,0.f}; hacc[f] = (f32x4){0.f,0.f,0.f,0.f}; }
        // t=0: inp == 0 -> gi is bias-only; skip the 24-chunk gi GEMM entirely.
        if (t > 0)
            dec_gemm(Wih, 768, 24, &inp16[0][0], 776, Wb[0], Wb[1], gacc, nbg, tid, r16, kq);
        dec_gemm(Whh, 256,  8, &h16d[0][0], 264, Wb[0], Wb[1], hacc, nbg, tid, r16, kq);
        // ---- GRU cell (lane-local) ----
#pragma unroll
        for (int d = 0; d < 2; ++d)
#pragma unroll
            for (int q = 0; q < 4; ++q) {
                float rr = frcp_(1.f + __expf(-(gacc[d][q] + bih[d] + hacc[d][q] + bhh[d])));
                float zz = frcp_(1.f + __expf(-(gacc[2 + d][q] + bih[2 + d] + hacc[2 + d][q] + bhh[2 + d])));
                float nn = tanhf(fmaf(rr, hacc[4 + d][q] + bhh[4 + d], gacc[4 + d][q] + bih[4 + d]));
                float hnew = (1.f - zz) * nn + zz * hreg[d][q];
                hreg[d][q] = hnew;
                h16d[kq * 4 + q][wv * 32 + d * 16 + r16] = f2bf_(hnew);
            }
        __syncthreads();
        // ---- inp' = relu(h @ Wfc^T + b_fc) ----
        if (t + 1 < NDAYS) {
            f32x4 iacc[6];
#pragma unroll
            for (int f = 0; f < 6; ++f) iacc[f] = (f32x4){0.f,0.f,0.f,0.f};
            dec_gemm(Wfc, 256, 8, &h16d[0][0], 264, Wb[0], Wb[1], iacc, nbf, tid, r16, kq);
#pragma unroll
            for (int f = 0; f < 6; ++f)
#pragma unroll
                for (int q = 0; q < 4; ++q)
                    inp16[kq * 4 + q][nbf[f] + r16] = f2bf_(fmaxf(iacc[f][q] + bfc6[f], 0.f));
        }
        // ---- fc_out: per-wave partials over its 32 cols, LDS reduce ----
        {
            float pq[2][4];
#pragma unroll
            for (int o = 0; o < 2; ++o)
#pragma unroll
                for (int q = 0; q < 4; ++q)
                    pq[o][q] = fmaf(hreg[0][q], fowr[o][0], hreg[1][q] * fowr[o][1]);
#pragma unroll
            for (int o = 0; o < 2; ++o)
#pragma unroll
                for (int q = 0; q < 4; ++q) {
                    float v = pq[o][q];
                    v += __shfl_xor(v, 1, 64); v += __shfl_xor(v, 2, 64);
                    v += __shfl_xor(v, 4, 64); v += __shfl_xor(v, 8, 64);
                    pq[o][q] = v;
                }
            if (r16 == 0) {
#pragma unroll
                for (int q = 0; q < 4; ++q) {
                    red_s[wv][kq * 4 + q][0] = pq[0][q];
                    red_s[wv][kq * 4 + q][1] = pq[1][q];
                }
            }
        }
        __syncthreads();
        if (tid < 16) {
            float l0 = fb0, l1 = fb1;
#pragma unroll
            for (int w = 0; w < 8; ++w) { l0 += red_s[w][tid][0]; l1 += red_s[w][tid][1]; }
            float mx = fmaxf(l0, l1);
            float e0 = __expf(l0 - mx), e1 = __expf(l1 - mx);
            float inv = frcp_(e0 + e1);
            float* op = outp + (size_t)(r0 + tid) * (NDAYS * OUTD) + t * OUTD;
            op[0] = e0 * inv; op[1] = e1 * inv;
        }
        __syncthreads();
    }
}

extern "C" void kernel_launch(void* const* d_in, const int* in_sizes, int n_in,
                              void* d_out, int out_size, void* d_ws, size_t ws_size,
                              hipStream_t stream)
{
    (void)in_sizes; (void)n_in; (void)out_size; (void)ws_size;
    const float* x        = (const float*)d_in[0];
    const int*   len      = (const int*)  d_in[1];
    const float* enc_w_ih = (const float*)d_in[2];
    const float* enc_w_hh = (const float*)d_in[3];
    const float* enc_bias = (const float*)d_in[4];
    const float* dec_w_ih = (const float*)d_in[5];
    const float* dec_w_hh = (const float*)d_in[6];
    const float* dec_b_ih = (const float*)d_in[7];
    const float* dec_b_hh = (const float*)d_in[8];
    const float* attn_w1  = (const float*)d_in[9];
    const float* attn_b1  = (const float*)d_in[10];
    const float* attn_w2  = (const float*)d_in[11];
    const float* attn_b2  = (const float*)d_in[12];
    const float* attn_v   = (const float*)d_in[13];
    const float* attn_bv  = (const float*)d_in[14];
    const float* fc_in_w  = (const float*)d_in[15];
    const float* fc_in_b  = (const float*)d_in[16];
    const float* fc_out_w = (const float*)d_in[17];
    const float* fc_out_b = (const float*)d_in[18];
    const float* span_w   = (const float*)d_in[19];
    const float* span_b   = (const float*)d_in[20];
    float* out = (float*)d_out;
    float* wsf = (float*)d_ws;

    const size_t ROWS = (size_t)B_ * T_;            // 38400
    float* UX    = wsf;                             // 38400*768
    float* Hfull = UX + ROWS * IN_;                 // 38400*256
    float* xs    = Hfull + ROWS * H_;               // 38400
    float* xnb   = xs + ROWS;                       // 38400
    float* WT    = xnb + ROWS;                      // 256*768 floats (packed enc weights)
    float* bvv   = WT + 256 * 768;                  // 768
    float* bvn   = bvv + 768;                       // 16 (3 used)
    float* UXN   = bvn + 16;                        // 38400*3
    float* UXS   = UXN + ROWS * 3;                  // 38400*3
    float* UXP2  = UXS + ROWS * 3;                  // 38400*6
    float* qbuf  = UXP2 + ROWS * 6;                 // 512*256
    float* scb   = qbuf + (size_t)B_ * H_;          // 38400
    float* ctx   = scb + ROWS;                      // 512*256
    float* wpool = ctx + (size_t)B_ * H_;           // bf16 weight pool
    unsigned int* WPK = (unsigned int*)WT;
    unsigned short* Wencbf = (unsigned short*)wpool;                 // 768*768
    unsigned short* W1bf   = Wencbf + (size_t)768 * 768;             // 256*256
    unsigned short* W2bf   = W1bf + (size_t)256 * 256;               // 256*256
    unsigned short* DWIHbf = W2bf + (size_t)256 * 256;               // 768*768
    unsigned short* DWHHbf = DWIHbf + (size_t)768 * 768;             // 768*256
    unsigned short* FCINbf = DWHHbf + (size_t)768 * 256;             // 768*256
    float* S1 = UX;   // reuse after encoder consumes UX

    k_bias<<<1, 256, 0, stream>>>(enc_bias, bvv, bvn);
    k_packw<<<128, 256, 0, stream>>>(enc_w_hh, WPK);
    k_cvt_all<<<(CV5 + 255) / 256, 256, 0, stream>>>(
        enc_w_ih, attn_w1, attn_w2, dec_w_ih, dec_w_hh, fc_in_w,
        Wencbf, W1bf, W2bf, DWIHbf, DWHHbf, FCINbf);
    // GEMM writes raw UX + per-gate norm partials + expmap0 row scale (xs/xnb, from A loads);
    // k_uxn turns partials into UXS/UXN.
    k_gemm_ux<<<dim3(4, (unsigned)(ROWS / 128)), 256, 0, stream>>>(x, Wencbf, UX, UXP2, xs, xnb);
    k_uxn<<<(unsigned)((ROWS * 3 + 255) / 256), 256, 0, stream>>>(UXP2, xs, xnb, UXS, UXN);
    k_encoder<<<B_ / 2, 512, 0, stream>>>(UX, WPK, bvv, bvn, UXN, UXS, Hfull);
    // Hfull is already logmapped. q = hx @ w2^T + b2 (hx = rows t=T-1, stride T*H)
    k_gemm_mfma_g<<<dim3(H_ / 128, B_ / 128), 256, 0, stream>>>(Hfull + (T_ - 1) * H_, T_ * H_, W2bf, attn_b2, qbuf, H_, H_, 0);
    k_gemm_mfma_g<<<dim3(H_ / 128, (unsigned)(ROWS / 128)), 256, 0, stream>>>(Hfull, H_, W1bf, nullptr, S1, H_, H_, 0);
    k_score<<<(unsigned)(ROWS / 4), 256, 0, stream>>>(S1, qbuf, attn_b1, attn_v, attn_bv, len, scb);
    k_ctx<<<B_, 256, 0, stream>>>(scb, Hfull, span_w, span_b, ctx, out);
    k_decoder<<<B_ / 16, 512, 0, stream>>>(ctx, DWIHbf, DWHHbf, FCINbf,
                                           dec_b_ih, dec_b_hh, fc_in_b,
                                           fc_out_w, fc_out_b, out + B_ * NSPAN);
}